// Round 5
// baseline (836.249 us; speedup 1.0000x reference)
//
#include <hip/hip_runtime.h>
#include <cstdint>
#include <cstddef>

#define EPS 1e-5f

typedef __attribute__((ext_vector_type(8))) short bf16x8;
typedef __attribute__((ext_vector_type(4))) float f32x4;
typedef __attribute__((ext_vector_type(16))) float f32x16;

__device__ __forceinline__ unsigned short rne_bf16(float f) {
  union { float f; unsigned int u; } v; v.f = f;
  unsigned int u = v.u;
  return (unsigned short)((u + 0x7fffu + ((u >> 16) & 1u)) >> 16);
}
__device__ __forceinline__ float bf16_to_f(unsigned short h) {
  union { unsigned int u; float f; } v; v.u = ((unsigned int)h) << 16; return v.f;
}
// split fp32 into hi/lo bf16 pair: hi+lo represents v to ~2^-17 relative
__device__ __forceinline__ void split_hl(float v, unsigned short& h, unsigned short& l) {
  h = rne_bf16(v);
  l = rne_bf16(v - bf16_to_f(h));
}
__device__ __forceinline__ f32x4 mfma16(bf16x8 a, bf16x8 b, f32x4 c) {
  return __builtin_amdgcn_mfma_f32_16x16x32_bf16(a, b, c, 0, 0, 0);
}
__device__ __forceinline__ f32x16 mfma32(bf16x8 a, bf16x8 b, f32x16 c) {
  return __builtin_amdgcn_mfma_f32_32x32x16_bf16(a, b, c, 0, 0, 0);
}

// ---------------------------------------------------------------------------
// Stage 1: fc1. h_t[b][k][m] = x[b]·fc1_w[m*128+k] + fc1_b.  One wave per row.
// HBM-bound on the 134 MB weight read (~21 us floor).
// ---------------------------------------------------------------------------
__global__ __launch_bounds__(256) void k_fc1(const float* __restrict__ x,
                                             const float* __restrict__ w,
                                             const float* __restrict__ bias,
                                             float* __restrict__ h_t) {
  const int lane = threadIdx.x & 63;
  const int wv = threadIdx.x >> 6;
  const int r = blockIdx.x * 4 + wv;               // weight row 0..32767
  const float4* wr = (const float4*)(w + (size_t)r * 1024);
  float acc[8] = {0, 0, 0, 0, 0, 0, 0, 0};
#pragma unroll
  for (int i = 0; i < 4; ++i) {
    float4 wv4 = wr[lane + i * 64];
#pragma unroll
    for (int b = 0; b < 8; ++b) {
      float4 xv = ((const float4*)(x + b * 1024))[lane + i * 64];
      acc[b] += wv4.x * xv.x + wv4.y * xv.y + wv4.z * xv.z + wv4.w * xv.w;
    }
  }
#pragma unroll
  for (int d = 1; d < 64; d <<= 1) {
#pragma unroll
    for (int b = 0; b < 8; ++b) acc[b] += __shfl_xor(acc[b], d);
  }
  if (lane == 0) {
    const int mm = r >> 7, kk = r & 127;
    const float bb = bias[r];
#pragma unroll
    for (int b = 0; b < 8; ++b) h_t[b * 32768 + kk * 256 + mm] = acc[b] + bb;
  }
}

// ---------------------------------------------------------------------------
// Stage 2a: conv1 + BN + ReLU (fp32).
// ---------------------------------------------------------------------------
__global__ __launch_bounds__(256) void k_conv1(
    const float* __restrict__ h_t,
    const float* __restrict__ c1q_w, const float* __restrict__ c1q_b,
    const float* __restrict__ c1v_w, const float* __restrict__ c1v_b,
    const float* __restrict__ g1q, const float* __restrict__ be1q,
    const float* __restrict__ mu1q, const float* __restrict__ va1q,
    const float* __restrict__ g1k, const float* __restrict__ be1k,
    const float* __restrict__ mu1k, const float* __restrict__ va1k,
    const float* __restrict__ g1v, const float* __restrict__ be1v,
    const float* __restrict__ mu1v, const float* __restrict__ va1v,
    float* __restrict__ T1q, float* __restrict__ T1k, float* __restrict__ T1v) {
  const int m = threadIdx.x;
  const int o = blockIdx.x & 63;
  const int b = blockIdx.x >> 6;
  const int path = blockIdx.y;
  const float* w = (path == 0 ? c1q_w : c1v_w) + o * 128;
  const float* h = h_t + b * 32768 + m;
  float acc = 0.f;
#pragma unroll 8
  for (int c = 0; c < 128; ++c) acc += w[c] * h[c * 256];
  if (path == 0) {
    const float z = acc + c1q_b[o];
    const float sq = g1q[o] / sqrtf(va1q[o] + EPS);
    T1q[b * 16384 + o * 256 + m] = fmaxf((z - mu1q[o]) * sq + be1q[o], 0.f);
    const float sk = g1k[o] / sqrtf(va1k[o] + EPS);
    T1k[b * 16384 + o * 256 + m] = fmaxf((z - mu1k[o]) * sk + be1k[o], 0.f);
  } else {
    const float z = acc + c1v_b[o];
    const float sv = g1v[o] / sqrtf(va1v[o] + EPS);
    T1v[b * 16384 + o * 256 + m] = fmaxf((z - mu1v[o]) * sv + be1v[o], 0.f);
  }
}

// ---------------------------------------------------------------------------
// Stage 2b: conv2 + BN + ReLU.  t[64] FULLY unrolled -> stays in VGPRs.
//   Q/K paths: output TRANSPOSED hi/lo bf16 [b][m(256)][c2(128)]
//   V path:    output fp32 V2F [b][c2(128)][m(256)]
// ---------------------------------------------------------------------------
__global__ __launch_bounds__(256) void k_conv2(
    const float* __restrict__ T1q, const float* __restrict__ T1k,
    const float* __restrict__ T1v,
    const float* __restrict__ c2q_w, const float* __restrict__ c2q_b,
    const float* __restrict__ c2v_w, const float* __restrict__ c2v_b,
    const float* __restrict__ g2q, const float* __restrict__ be2q,
    const float* __restrict__ mu2q, const float* __restrict__ va2q,
    const float* __restrict__ g2k, const float* __restrict__ be2k,
    const float* __restrict__ mu2k, const float* __restrict__ va2k,
    const float* __restrict__ g2v, const float* __restrict__ be2v,
    const float* __restrict__ mu2v, const float* __restrict__ va2v,
    unsigned short* __restrict__ Q2H, unsigned short* __restrict__ Q2L,
    unsigned short* __restrict__ K2H, unsigned short* __restrict__ K2L,
    float* __restrict__ V2F) {
  const int m = threadIdx.x;
  const int b = blockIdx.x;
  const int path = blockIdx.y;
  const int oc = blockIdx.z;
  const float* T1 = (path == 0 ? T1q : path == 1 ? T1k : T1v) + b * 16384 + m;
  const float* w = (path == 2 ? c2v_w : c2q_w);
  const float* cb = (path == 2 ? c2v_b : c2q_b);
  const float* g = (path == 0 ? g2q : path == 1 ? g2k : g2v);
  const float* be = (path == 0 ? be2q : path == 1 ? be2k : be2v);
  const float* mu = (path == 0 ? mu2q : path == 1 ? mu2k : mu2v);
  const float* va = (path == 0 ? va2q : path == 1 ? va2k : va2v);
  float t[64];
#pragma unroll
  for (int c = 0; c < 64; ++c) t[c] = T1[c * 256];
  unsigned short* oh =
      (path == 0 ? Q2H : K2H) + b * 32768 + m * 128 + oc * 64;
  unsigned short* ol =
      (path == 0 ? Q2L : K2L) + b * 32768 + m * 128 + oc * 64;
  for (int og = 0; og < 8; ++og) {
    bf16x8 ph, pl;
#pragma unroll
    for (int j = 0; j < 8; ++j) {
      const int o = oc * 64 + og * 8 + j;
      float acc = cb[o];
      const float* wo = w + o * 64;
#pragma unroll
      for (int c = 0; c < 64; ++c) acc += wo[c] * t[c];
      const float s = g[o] / sqrtf(va[o] + EPS);
      const float val = fmaxf((acc - mu[o]) * s + be[o], 0.f);
      if (path == 2) {
        V2F[b * 32768 + o * 256 + m] = val;
      } else {
        unsigned short hh, ll;
        split_hl(val, hh, ll);
        ph[j] = (short)hh; pl[j] = (short)ll;
      }
    }
    if (path != 2) {
      *(bf16x8*)(oh + og * 8) = ph;
      *(bf16x8*)(ol + og * 8) = pl;
    }
  }
}

// ---------------------------------------------------------------------------
// Stage 3 merged: z=0 -> conv3-Q (scale folds 1/sqrt(128)*log2(e) for the
// exp2 softmax), z=1 -> conv3-K, z=2 (x<16) -> U + Vpp (co_w-projected V).
// ---------------------------------------------------------------------------
__global__ __launch_bounds__(256) void k_conv3all(
    const float* __restrict__ c3q_w, const float* __restrict__ c3q_b,
    const float* __restrict__ c3k_w, const float* __restrict__ c3k_b,
    const unsigned short* __restrict__ Q2H, const unsigned short* __restrict__ Q2L,
    const unsigned short* __restrict__ K2H, const unsigned short* __restrict__ K2L,
    unsigned short* __restrict__ QhB, unsigned short* __restrict__ QlB,
    unsigned short* __restrict__ KhB, unsigned short* __restrict__ KlB,
    const float* __restrict__ c3v_w, const float* __restrict__ c3v_b,
    const float* __restrict__ V2F, const float* __restrict__ co_w,
    float4* __restrict__ Vpp) {
  const int z = blockIdx.z;
  const int b = blockIdx.y;
  if (z == 2) {
    if (blockIdx.x >= 16) return;
    __shared__ float Us[387];
    __shared__ float Up[256][3];
    const int tt = threadIdx.x;
    {  // U[c][o] = sum_m V2F[b][c][m]*co_w[o][m]; pair-split over m halves
      const int c = tt >> 1, mh = tt & 1;
      const float* v = V2F + b * 32768 + c * 256 + mh * 128;
      const float* cw0 = co_w + mh * 128;
      float u0 = 0.f, u1 = 0.f, u2 = 0.f;
#pragma unroll 4
      for (int mm = 0; mm < 128; ++mm) {
        const float xv = v[mm];
        u0 += xv * cw0[mm];
        u1 += xv * cw0[256 + mm];
        u2 += xv * cw0[512 + mm];
      }
      Up[tt][0] = u0; Up[tt][1] = u1; Up[tt][2] = u2;
      if (tt < 3) {  // col-sums of co_w (for the bias term)
        float s = 0.f;
        for (int mm = 0; mm < 256; ++mm) s += co_w[tt * 256 + mm];
        Us[384 + tt] = s;
      }
    }
    __syncthreads();
    if ((tt & 1) == 0) {
      const int c = tt >> 1;
      Us[c * 3 + 0] = Up[tt][0] + Up[tt + 1][0];
      Us[c * 3 + 1] = Up[tt][1] + Up[tt + 1][1];
      Us[c * 3 + 2] = Up[tt][2] + Up[tt + 1][2];
    }
    __syncthreads();
    const int n = blockIdx.x * 256 + tt;
    const float* w = c3v_w + (size_t)n * 128;
    float a0 = 0.f, a1 = 0.f, a2 = 0.f;
#pragma unroll 4
    for (int c = 0; c < 128; ++c) {
      const float wc = w[c];
      a0 += wc * Us[c * 3 + 0];
      a1 += wc * Us[c * 3 + 1];
      a2 += wc * Us[c * 3 + 2];
    }
    const float bb = c3v_b[n];
    Vpp[(size_t)b * 4096 + n] =
        make_float4(a0 + bb * Us[384], a1 + bb * Us[385], a2 + bb * Us[386], 0.f);
    return;
  }
  // z=0: Q, z=1: K — split-MFMA conv3, output hi/lo bf16 pair Y[b][n][m]
  const float* W = (z == 0) ? c3q_w : c3k_w;
  const float* bias = (z == 0) ? c3q_b : c3k_b;
  const unsigned short* Xh = (z == 0) ? Q2H : K2H;
  const unsigned short* Xl = (z == 0) ? Q2L : K2L;
  unsigned short* Yh = (z == 0) ? QhB : KhB;
  unsigned short* Yl = (z == 0) ? QlB : KlB;
  const float scale = (z == 0) ? 0.08838834764831845f * 1.4426950408889634f : 1.0f;
  const int lane = threadIdx.x & 63, wv = threadIdx.x >> 6;
  const int l15 = lane & 15, quad = lane >> 4;
  const unsigned short* XH = Xh + b * 32768;
  const unsigned short* XL = Xl + b * 32768;
  unsigned short* YH = Yh + (size_t)b * 4096 * 256;
  unsigned short* YL = Yl + (size_t)b * 4096 * 256;
  const int nb = blockIdx.x * 64 + wv * 16;
  const float* wr = W + (size_t)(nb + l15) * 128 + quad * 8;
  bf16x8 ah[4], al[4];
#pragma unroll
  for (int ks = 0; ks < 4; ++ks) {
#pragma unroll
    for (int j = 0; j < 8; ++j) {
      unsigned short hh, ll;
      split_hl(wr[ks * 32 + j], hh, ll);
      ah[ks][j] = (short)hh; al[ks][j] = (short)ll;
    }
  }
  f32x4 acc[16];
#pragma unroll
  for (int ms = 0; ms < 16; ++ms) acc[ms] = (f32x4){0, 0, 0, 0};
#pragma unroll
  for (int ks = 0; ks < 4; ++ks) {
#pragma unroll
    for (int ms = 0; ms < 16; ++ms) {
      const size_t off = (size_t)(ms * 16 + l15) * 128 + ks * 32 + quad * 8;
      bf16x8 bh = *(const bf16x8*)(XH + off);
      bf16x8 bl = *(const bf16x8*)(XL + off);
      acc[ms] = mfma16(ah[ks], bh, acc[ms]);
      acc[ms] = mfma16(al[ks], bh, acc[ms]);
      acc[ms] = mfma16(ah[ks], bl, acc[ms]);
    }
  }
#pragma unroll
  for (int r = 0; r < 4; ++r) {
    const int n = nb + quad * 4 + r;
    const float bv = bias[n];
#pragma unroll
    for (int ms = 0; ms < 16; ++ms) {
      const float v = (acc[ms][r] + bv) * scale;
      unsigned short hh, ll;
      split_hl(v, hh, ll);
      YH[(size_t)n * 256 + ms * 16 + l15] = hh;
      YL[(size_t)n * 256 + ms * 16 + l15] = ll;
    }
  }
}

// ---------------------------------------------------------------------------
// Stage 4: attention, PV collapsed into rank-3 co_w projection, exp2 softmax.
// SINGLE-buffered K tile (34.3 KB LDS) -> 4 blocks/CU (16 waves/CU); latency
// hidden by TLP instead of double-buffering (r0->r1 showed occupancy is the
// dominant lever for this latency-bound kernel).  j-range split in 4 (grid
// 1024 = 8b x 32qt x 4jq) to fill 4 blocks/CU.  Three S accumulators = three
// 16-long MFMA chains.  __launch_bounds__(256,4): VGPR cap 128 = the measured
// natural allocation of this structure (r3 VGPR_Count=128), so no new spill.
// ---------------------------------------------------------------------------
__global__ __launch_bounds__(256, 4) void k_attn(
    const unsigned short* __restrict__ Qh, const unsigned short* __restrict__ Ql,
    const unsigned short* __restrict__ Kh, const unsigned short* __restrict__ Kl,
    const float4* __restrict__ Vpp, float4* __restrict__ part) {
  __shared__ __align__(16) short Kth[32 * 264];   // K hi tile [32][256] pad 264
  __shared__ __align__(16) short Ktl[32 * 264];   // K lo tile
  __shared__ __align__(16) float4 Vt[32];         // projected V tile
  const int t = threadIdx.x;
  const int lane = t & 63, wv = t >> 6;
  const int l31 = lane & 31, half = lane >> 5;
  const int b = blockIdx.x & 7;       // batch ~pinned per-XCD for K L2 locality
  const int qt = (blockIdx.x >> 3) & 31;
  const int jq = blockIdx.x >> 8;     // j-quarter 0..3
  const int qrow = qt * 128 + wv * 32 + l31;
  const size_t qoff = ((size_t)b * 4096 + qrow) * 256 + half * 8;
  bf16x8 qfh[16], qfl[16];            // Q hi/lo (B-operand layout)
#pragma unroll
  for (int kc = 0; kc < 16; ++kc) {
    qfh[kc] = *(const bf16x8*)(Qh + qoff + kc * 16);
    qfl[kc] = *(const bf16x8*)(Ql + qoff + kc * 16);
  }
  const unsigned short* Kgh = Kh + (size_t)b * 4096 * 256;
  const unsigned short* Kgl = Kl + (size_t)b * 4096 * 256;
  const float4* Vg = Vpp + (size_t)b * 4096;
  const int r0 = t >> 5;              // staging row within 8-row group
  const int sseg = (t & 31) * 8;      // staging column segment
  float a0 = 0.f, a1 = 0.f, a2 = 0.f, al = 0.f;
  const int jt0 = jq * 32;
  for (int jt = jt0; jt < jt0 + 32; ++jt) {
    const int jbase = jt * 32;
    __syncthreads();                  // previous compute done before overwrite
#pragma unroll
    for (int i = 0; i < 4; ++i) {     // stage K hi/lo [32 rows][256]
      const int row = i * 8 + r0;
      const size_t g = (size_t)(jbase + row) * 256 + sseg;
      *(bf16x8*)&Kth[row * 264 + sseg] = *(const bf16x8*)(Kgh + g);
      *(bf16x8*)&Ktl[row * 264 + sseg] = *(const bf16x8*)(Kgl + g);
    }
    if (t < 32) Vt[t] = Vg[jbase + t];
    __syncthreads();
    // S^T[32j][32q] = K·Q^T; three accumulators = three 16-long MFMA chains
    f32x16 sA, sB, sC;
#pragma unroll
    for (int r = 0; r < 16; ++r) { sA[r] = 0.f; sB[r] = 0.f; sC[r] = 0.f; }
#pragma unroll
    for (int kc = 0; kc < 16; ++kc) {
      bf16x8 kh = *(const bf16x8*)&Kth[l31 * 264 + kc * 16 + half * 8];
      bf16x8 kl = *(const bf16x8*)&Ktl[l31 * 264 + kc * 16 + half * 8];
      sA = mfma32(kh, qfh[kc], sA);   // Kh·Qh
      sB = mfma32(kh, qfl[kc], sB);   // Kh·Ql
      sC = mfma32(kl, qfh[kc], sC);   // Kl·Qh
    }
#pragma unroll
    for (int r = 0; r < 16; ++r) {
      const float p = __builtin_amdgcn_exp2f(sA[r] + sB[r] + sC[r]);
      const float4 vj = Vt[(r & 3) + 8 * (r >> 2) + 4 * half];
      a0 += p * vj.x; a1 += p * vj.y; a2 += p * vj.z; al += p;
    }
  }
  // halves hold disjoint j-sets for the same q: one swap-add finishes the sum
  a0 += __shfl_xor(a0, 32);
  a1 += __shfl_xor(a1, 32);
  a2 += __shfl_xor(a2, 32);
  al += __shfl_xor(al, 32);
  if (half == 0)
    part[(size_t)jq * 32768 + (size_t)b * 4096 + qrow] =
        make_float4(a0, a1, a2, al);
}

// ---------------------------------------------------------------------------
// Stage 5: combine the four j-quarter partials; out = num/l + co_b.
// ---------------------------------------------------------------------------
__global__ __launch_bounds__(256) void k_combine(
    const float4* __restrict__ part, const float* __restrict__ co_b,
    float* __restrict__ out) {
  const int i = blockIdx.x * 256 + threadIdx.x;   // b*4096 + q
  const float4 p0 = part[i];
  const float4 p1 = part[32768 + i];
  const float4 p2 = part[65536 + i];
  const float4 p3 = part[98304 + i];
  const float rl = 1.f / (p0.w + p1.w + p2.w + p3.w);
  out[(size_t)i * 3 + 0] = (p0.x + p1.x + p2.x + p3.x) * rl + co_b[0];
  out[(size_t)i * 3 + 1] = (p0.y + p1.y + p2.y + p3.y) * rl + co_b[1];
  out[(size_t)i * 3 + 2] = (p0.z + p1.z + p2.z + p3.z) * rl + co_b[2];
}

// ---------------------------------------------------------------------------
extern "C" void kernel_launch(void* const* d_in, const int* in_sizes, int n_in,
                              void* d_out, int out_size, void* d_ws, size_t ws_size,
                              hipStream_t stream) {
  const float* x = (const float*)d_in[0];
  const float* fc1_w = (const float*)d_in[1];
  const float* fc1_b = (const float*)d_in[2];
  const float* c1q_w = (const float*)d_in[3];
  const float* c1q_b = (const float*)d_in[4];
  const float* c2q_w = (const float*)d_in[5];
  const float* c2q_b = (const float*)d_in[6];
  const float* c3q_w = (const float*)d_in[7];
  const float* c3q_b = (const float*)d_in[8];
  const float* c3k_w = (const float*)d_in[9];
  const float* c3k_b = (const float*)d_in[10];
  const float* c1v_w = (const float*)d_in[11];
  const float* c1v_b = (const float*)d_in[12];
  const float* c2v_w = (const float*)d_in[13];
  const float* c2v_b = (const float*)d_in[14];
  const float* c3v_w = (const float*)d_in[15];
  const float* c3v_b = (const float*)d_in[16];
  const float* bn1q_g = (const float*)d_in[17];
  const float* bn1q_be = (const float*)d_in[18];
  const float* bn1q_m = (const float*)d_in[19];
  const float* bn1q_v = (const float*)d_in[20];
  const float* bn2q_g = (const float*)d_in[21];
  const float* bn2q_be = (const float*)d_in[22];
  const float* bn2q_m = (const float*)d_in[23];
  const float* bn2q_v = (const float*)d_in[24];
  const float* bn1k_g = (const float*)d_in[25];
  const float* bn1k_be = (const float*)d_in[26];
  const float* bn1k_m = (const float*)d_in[27];
  const float* bn1k_v = (const float*)d_in[28];
  const float* bn2k_g = (const float*)d_in[29];
  const float* bn2k_be = (const float*)d_in[30];
  const float* bn2k_m = (const float*)d_in[31];
  const float* bn2k_v = (const float*)d_in[32];
  const float* bn1v_g = (const float*)d_in[33];
  const float* bn1v_be = (const float*)d_in[34];
  const float* bn1v_m = (const float*)d_in[35];
  const float* bn1v_v = (const float*)d_in[36];
  const float* bn2v_g = (const float*)d_in[37];
  const float* bn2v_be = (const float*)d_in[38];
  const float* bn2v_m = (const float*)d_in[39];
  const float* bn2v_v = (const float*)d_in[40];
  const float* co_w = (const float*)d_in[41];
  const float* co_b = (const float*)d_in[42];

  char* ws = (char*)d_ws;
  float* h_t = (float*)(ws + 0);                            // 1 MB [8][128][256]
  float* T1q = (float*)(ws + 1048576);                      // 512KB each
  float* T1k = (float*)(ws + 1572864);
  float* T1v = (float*)(ws + 2097152);
  unsigned short* Q2H = (unsigned short*)(ws + 2621440);    // 512KB each, [8][256][128]
  unsigned short* Q2L = (unsigned short*)(ws + 3145728);
  unsigned short* K2H = (unsigned short*)(ws + 3670016);
  unsigned short* K2L = (unsigned short*)(ws + 4194304);
  float* V2F = (float*)(ws + 4718592);                      // 1MB fp32 [8][128][256]
  unsigned short* QhB = (unsigned short*)(ws + 5767168);    // 16MB each, [8][4096][256]
  unsigned short* QlB = (unsigned short*)(ws + 22544384);
  unsigned short* KhB = (unsigned short*)(ws + 39321600);
  unsigned short* KlB = (unsigned short*)(ws + 56098816);
  float4* Vpp = (float4*)(ws + 72876032);                   // 512KB [8][4096] f4
  float4* part = (float4*)(ws + 73416704);                  // 2MB [4][8][4096] f4
  // total ws usage: ~72 MB

  k_fc1<<<8192, 256, 0, stream>>>(x, fc1_w, fc1_b, h_t);
  k_conv1<<<dim3(512, 2), 256, 0, stream>>>(
      h_t, c1q_w, c1q_b, c1v_w, c1v_b,
      bn1q_g, bn1q_be, bn1q_m, bn1q_v,
      bn1k_g, bn1k_be, bn1k_m, bn1k_v,
      bn1v_g, bn1v_be, bn1v_m, bn1v_v,
      T1q, T1k, T1v);
  k_conv2<<<dim3(8, 3, 2), 256, 0, stream>>>(
      T1q, T1k, T1v, c2q_w, c2q_b, c2v_w, c2v_b,
      bn2q_g, bn2q_be, bn2q_m, bn2q_v,
      bn2k_g, bn2k_be, bn2k_m, bn2k_v,
      bn2v_g, bn2v_be, bn2v_m, bn2v_v,
      Q2H, Q2L, K2H, K2L, V2F);
  k_conv3all<<<dim3(64, 8, 3), 256, 0, stream>>>(
      c3q_w, c3q_b, c3k_w, c3k_b, Q2H, Q2L, K2H, K2L,
      QhB, QlB, KhB, KlB, c3v_w, c3v_b, V2F, co_w, Vpp);
  k_attn<<<1024, 256, 0, stream>>>(QhB, QlB, KhB, KlB, Vpp, part);
  k_combine<<<128, 256, 0, stream>>>(part, co_b, (float*)d_out);
}

// Round 6
// 706.962 us; speedup vs baseline: 1.1829x; 1.1829x over previous
//
#include <hip/hip_runtime.h>
#include <cstdint>
#include <cstddef>

#define EPS 1e-5f

typedef __attribute__((ext_vector_type(8))) short bf16x8;
typedef __attribute__((ext_vector_type(4))) float f32x4;
typedef __attribute__((ext_vector_type(16))) float f32x16;

__device__ __forceinline__ unsigned short rne_bf16(float f) {
  union { float f; unsigned int u; } v; v.f = f;
  unsigned int u = v.u;
  return (unsigned short)((u + 0x7fffu + ((u >> 16) & 1u)) >> 16);
}
__device__ __forceinline__ float bf16_to_f(unsigned short h) {
  union { unsigned int u; float f; } v; v.u = ((unsigned int)h) << 16; return v.f;
}
// split fp32 into hi/lo bf16 pair: hi+lo represents v to ~2^-17 relative
__device__ __forceinline__ void split_hl(float v, unsigned short& h, unsigned short& l) {
  h = rne_bf16(v);
  l = rne_bf16(v - bf16_to_f(h));
}
__device__ __forceinline__ f32x4 mfma16(bf16x8 a, bf16x8 b, f32x4 c) {
  return __builtin_amdgcn_mfma_f32_16x16x32_bf16(a, b, c, 0, 0, 0);
}
__device__ __forceinline__ f32x16 mfma32(bf16x8 a, bf16x8 b, f32x16 c) {
  return __builtin_amdgcn_mfma_f32_32x32x16_bf16(a, b, c, 0, 0, 0);
}

// ---------------------------------------------------------------------------
// Stage 1: fc1. h_t[b][k][m] = x[b]·fc1_w[m*128+k] + fc1_b.  One wave per row.
// HBM-bound on the 134 MB weight read (~21 us floor).
// ---------------------------------------------------------------------------
__global__ __launch_bounds__(256) void k_fc1(const float* __restrict__ x,
                                             const float* __restrict__ w,
                                             const float* __restrict__ bias,
                                             float* __restrict__ h_t) {
  const int lane = threadIdx.x & 63;
  const int wv = threadIdx.x >> 6;
  const int r = blockIdx.x * 4 + wv;               // weight row 0..32767
  const float4* wr = (const float4*)(w + (size_t)r * 1024);
  float acc[8] = {0, 0, 0, 0, 0, 0, 0, 0};
#pragma unroll
  for (int i = 0; i < 4; ++i) {
    float4 wv4 = wr[lane + i * 64];
#pragma unroll
    for (int b = 0; b < 8; ++b) {
      float4 xv = ((const float4*)(x + b * 1024))[lane + i * 64];
      acc[b] += wv4.x * xv.x + wv4.y * xv.y + wv4.z * xv.z + wv4.w * xv.w;
    }
  }
#pragma unroll
  for (int d = 1; d < 64; d <<= 1) {
#pragma unroll
    for (int b = 0; b < 8; ++b) acc[b] += __shfl_xor(acc[b], d);
  }
  if (lane == 0) {
    const int mm = r >> 7, kk = r & 127;
    const float bb = bias[r];
#pragma unroll
    for (int b = 0; b < 8; ++b) h_t[b * 32768 + kk * 256 + mm] = acc[b] + bb;
  }
}

// ---------------------------------------------------------------------------
// Stage 2a: conv1 + BN + ReLU (fp32).
// ---------------------------------------------------------------------------
__global__ __launch_bounds__(256) void k_conv1(
    const float* __restrict__ h_t,
    const float* __restrict__ c1q_w, const float* __restrict__ c1q_b,
    const float* __restrict__ c1v_w, const float* __restrict__ c1v_b,
    const float* __restrict__ g1q, const float* __restrict__ be1q,
    const float* __restrict__ mu1q, const float* __restrict__ va1q,
    const float* __restrict__ g1k, const float* __restrict__ be1k,
    const float* __restrict__ mu1k, const float* __restrict__ va1k,
    const float* __restrict__ g1v, const float* __restrict__ be1v,
    const float* __restrict__ mu1v, const float* __restrict__ va1v,
    float* __restrict__ T1q, float* __restrict__ T1k, float* __restrict__ T1v) {
  const int m = threadIdx.x;
  const int o = blockIdx.x & 63;
  const int b = blockIdx.x >> 6;
  const int path = blockIdx.y;
  const float* w = (path == 0 ? c1q_w : c1v_w) + o * 128;
  const float* h = h_t + b * 32768 + m;
  float acc = 0.f;
#pragma unroll 8
  for (int c = 0; c < 128; ++c) acc += w[c] * h[c * 256];
  if (path == 0) {
    const float z = acc + c1q_b[o];
    const float sq = g1q[o] / sqrtf(va1q[o] + EPS);
    T1q[b * 16384 + o * 256 + m] = fmaxf((z - mu1q[o]) * sq + be1q[o], 0.f);
    const float sk = g1k[o] / sqrtf(va1k[o] + EPS);
    T1k[b * 16384 + o * 256 + m] = fmaxf((z - mu1k[o]) * sk + be1k[o], 0.f);
  } else {
    const float z = acc + c1v_b[o];
    const float sv = g1v[o] / sqrtf(va1v[o] + EPS);
    T1v[b * 16384 + o * 256 + m] = fmaxf((z - mu1v[o]) * sv + be1v[o], 0.f);
  }
}

// ---------------------------------------------------------------------------
// Stage 2b: conv2 + BN + ReLU.  t[64] FULLY unrolled -> stays in VGPRs.
//   Q/K paths: output TRANSPOSED hi/lo bf16 [b][m(256)][c2(128)]
//   V path:    output fp32 V2F [b][c2(128)][m(256)]
// ---------------------------------------------------------------------------
__global__ __launch_bounds__(256) void k_conv2(
    const float* __restrict__ T1q, const float* __restrict__ T1k,
    const float* __restrict__ T1v,
    const float* __restrict__ c2q_w, const float* __restrict__ c2q_b,
    const float* __restrict__ c2v_w, const float* __restrict__ c2v_b,
    const float* __restrict__ g2q, const float* __restrict__ be2q,
    const float* __restrict__ mu2q, const float* __restrict__ va2q,
    const float* __restrict__ g2k, const float* __restrict__ be2k,
    const float* __restrict__ mu2k, const float* __restrict__ va2k,
    const float* __restrict__ g2v, const float* __restrict__ be2v,
    const float* __restrict__ mu2v, const float* __restrict__ va2v,
    unsigned short* __restrict__ Q2H, unsigned short* __restrict__ Q2L,
    unsigned short* __restrict__ K2H, unsigned short* __restrict__ K2L,
    float* __restrict__ V2F) {
  const int m = threadIdx.x;
  const int b = blockIdx.x;
  const int path = blockIdx.y;
  const int oc = blockIdx.z;
  const float* T1 = (path == 0 ? T1q : path == 1 ? T1k : T1v) + b * 16384 + m;
  const float* w = (path == 2 ? c2v_w : c2q_w);
  const float* cb = (path == 2 ? c2v_b : c2q_b);
  const float* g = (path == 0 ? g2q : path == 1 ? g2k : g2v);
  const float* be = (path == 0 ? be2q : path == 1 ? be2k : be2v);
  const float* mu = (path == 0 ? mu2q : path == 1 ? mu2k : mu2v);
  const float* va = (path == 0 ? va2q : path == 1 ? va2k : va2v);
  float t[64];
#pragma unroll
  for (int c = 0; c < 64; ++c) t[c] = T1[c * 256];
  unsigned short* oh =
      (path == 0 ? Q2H : K2H) + b * 32768 + m * 128 + oc * 64;
  unsigned short* ol =
      (path == 0 ? Q2L : K2L) + b * 32768 + m * 128 + oc * 64;
  for (int og = 0; og < 8; ++og) {
    bf16x8 ph, pl;
#pragma unroll
    for (int j = 0; j < 8; ++j) {
      const int o = oc * 64 + og * 8 + j;
      float acc = cb[o];
      const float* wo = w + o * 64;
#pragma unroll
      for (int c = 0; c < 64; ++c) acc += wo[c] * t[c];
      const float s = g[o] / sqrtf(va[o] + EPS);
      const float val = fmaxf((acc - mu[o]) * s + be[o], 0.f);
      if (path == 2) {
        V2F[b * 32768 + o * 256 + m] = val;
      } else {
        unsigned short hh, ll;
        split_hl(val, hh, ll);
        ph[j] = (short)hh; pl[j] = (short)ll;
      }
    }
    if (path != 2) {
      *(bf16x8*)(oh + og * 8) = ph;
      *(bf16x8*)(ol + og * 8) = pl;
    }
  }
}

// ---------------------------------------------------------------------------
// Stage 3 merged: z=0 -> conv3-Q (scale folds 1/sqrt(128)*log2(e) for the
// exp2 softmax), z=1 -> conv3-K, z=2 (x<16) -> U + Vpp (co_w-projected V).
// ---------------------------------------------------------------------------
__global__ __launch_bounds__(256) void k_conv3all(
    const float* __restrict__ c3q_w, const float* __restrict__ c3q_b,
    const float* __restrict__ c3k_w, const float* __restrict__ c3k_b,
    const unsigned short* __restrict__ Q2H, const unsigned short* __restrict__ Q2L,
    const unsigned short* __restrict__ K2H, const unsigned short* __restrict__ K2L,
    unsigned short* __restrict__ QhB, unsigned short* __restrict__ QlB,
    unsigned short* __restrict__ KhB, unsigned short* __restrict__ KlB,
    const float* __restrict__ c3v_w, const float* __restrict__ c3v_b,
    const float* __restrict__ V2F, const float* __restrict__ co_w,
    float4* __restrict__ Vpp) {
  const int z = blockIdx.z;
  const int b = blockIdx.y;
  if (z == 2) {
    if (blockIdx.x >= 16) return;
    __shared__ float Us[387];
    __shared__ float Up[256][3];
    const int tt = threadIdx.x;
    {  // U[c][o] = sum_m V2F[b][c][m]*co_w[o][m]; pair-split over m halves
      const int c = tt >> 1, mh = tt & 1;
      const float* v = V2F + b * 32768 + c * 256 + mh * 128;
      const float* cw0 = co_w + mh * 128;
      float u0 = 0.f, u1 = 0.f, u2 = 0.f;
#pragma unroll 4
      for (int mm = 0; mm < 128; ++mm) {
        const float xv = v[mm];
        u0 += xv * cw0[mm];
        u1 += xv * cw0[256 + mm];
        u2 += xv * cw0[512 + mm];
      }
      Up[tt][0] = u0; Up[tt][1] = u1; Up[tt][2] = u2;
      if (tt < 3) {  // col-sums of co_w (for the bias term)
        float s = 0.f;
        for (int mm = 0; mm < 256; ++mm) s += co_w[tt * 256 + mm];
        Us[384 + tt] = s;
      }
    }
    __syncthreads();
    if ((tt & 1) == 0) {
      const int c = tt >> 1;
      Us[c * 3 + 0] = Up[tt][0] + Up[tt + 1][0];
      Us[c * 3 + 1] = Up[tt][1] + Up[tt + 1][1];
      Us[c * 3 + 2] = Up[tt][2] + Up[tt + 1][2];
    }
    __syncthreads();
    const int n = blockIdx.x * 256 + tt;
    const float* w = c3v_w + (size_t)n * 128;
    float a0 = 0.f, a1 = 0.f, a2 = 0.f;
#pragma unroll 4
    for (int c = 0; c < 128; ++c) {
      const float wc = w[c];
      a0 += wc * Us[c * 3 + 0];
      a1 += wc * Us[c * 3 + 1];
      a2 += wc * Us[c * 3 + 2];
    }
    const float bb = c3v_b[n];
    Vpp[(size_t)b * 4096 + n] =
        make_float4(a0 + bb * Us[384], a1 + bb * Us[385], a2 + bb * Us[386], 0.f);
    return;
  }
  // z=0: Q, z=1: K — split-MFMA conv3, output hi/lo bf16 pair Y[b][n][m]
  const float* W = (z == 0) ? c3q_w : c3k_w;
  const float* bias = (z == 0) ? c3q_b : c3k_b;
  const unsigned short* Xh = (z == 0) ? Q2H : K2H;
  const unsigned short* Xl = (z == 0) ? Q2L : K2L;
  unsigned short* Yh = (z == 0) ? QhB : KhB;
  unsigned short* Yl = (z == 0) ? QlB : KlB;
  const float scale = (z == 0) ? 0.08838834764831845f * 1.4426950408889634f : 1.0f;
  const int lane = threadIdx.x & 63, wv = threadIdx.x >> 6;
  const int l15 = lane & 15, quad = lane >> 4;
  const unsigned short* XH = Xh + b * 32768;
  const unsigned short* XL = Xl + b * 32768;
  unsigned short* YH = Yh + (size_t)b * 4096 * 256;
  unsigned short* YL = Yl + (size_t)b * 4096 * 256;
  const int nb = blockIdx.x * 64 + wv * 16;
  const float* wr = W + (size_t)(nb + l15) * 128 + quad * 8;
  bf16x8 ah[4], al[4];
#pragma unroll
  for (int ks = 0; ks < 4; ++ks) {
#pragma unroll
    for (int j = 0; j < 8; ++j) {
      unsigned short hh, ll;
      split_hl(wr[ks * 32 + j], hh, ll);
      ah[ks][j] = (short)hh; al[ks][j] = (short)ll;
    }
  }
  f32x4 acc[16];
#pragma unroll
  for (int ms = 0; ms < 16; ++ms) acc[ms] = (f32x4){0, 0, 0, 0};
#pragma unroll
  for (int ks = 0; ks < 4; ++ks) {
#pragma unroll
    for (int ms = 0; ms < 16; ++ms) {
      const size_t off = (size_t)(ms * 16 + l15) * 128 + ks * 32 + quad * 8;
      bf16x8 bh = *(const bf16x8*)(XH + off);
      bf16x8 bl = *(const bf16x8*)(XL + off);
      acc[ms] = mfma16(ah[ks], bh, acc[ms]);
      acc[ms] = mfma16(al[ks], bh, acc[ms]);
      acc[ms] = mfma16(ah[ks], bl, acc[ms]);
    }
  }
#pragma unroll
  for (int r = 0; r < 4; ++r) {
    const int n = nb + quad * 4 + r;
    const float bv = bias[n];
#pragma unroll
    for (int ms = 0; ms < 16; ++ms) {
      const float v = (acc[ms][r] + bv) * scale;
      unsigned short hh, ll;
      split_hl(v, hh, ll);
      YH[(size_t)n * 256 + ms * 16 + l15] = hh;
      YL[(size_t)n * 256 + ms * 16 + l15] = ll;
    }
  }
}

// ---------------------------------------------------------------------------
// Stage 4: attention (r3 structure: double-buffered K tiles, 1 barrier/tile,
// 2 blocks/CU, Q resident in regs) + 3-acc MFMA chain split + setprio around
// the MFMA cluster.  Combine stage FUSED via device-scope atomics: each (b,q)
// has exactly 2 contributors (jh=0/1); both atomicAdd partials, an atomic
// counter elects the last arriver to finalize (no dispatch-order assumption).
// ---------------------------------------------------------------------------
__global__ __launch_bounds__(256, 2) void k_attn(
    const unsigned short* __restrict__ Qh, const unsigned short* __restrict__ Ql,
    const unsigned short* __restrict__ Kh, const unsigned short* __restrict__ Kl,
    const float4* __restrict__ Vpp, float* __restrict__ partsum,
    unsigned int* __restrict__ cnt, const float* __restrict__ co_b,
    float* __restrict__ out) {
  __shared__ __align__(16) short Kt[2][2][32 * 264];  // [buf][hi/lo][32 rows pad 264]
  __shared__ __align__(16) float4 Vt[2][32];
  const int t = threadIdx.x;
  const int lane = t & 63, wv = t >> 6;
  const int l31 = lane & 31, half = lane >> 5;
  const int b = blockIdx.x & 7;       // batch ~pinned per-XCD for K L2 locality
  const int qt = (blockIdx.x >> 3) & 31;
  const int jh = blockIdx.x >> 8;     // j-half 0/1
  const int qrow = qt * 128 + wv * 32 + l31;
  const size_t qoff = ((size_t)b * 4096 + qrow) * 256 + half * 8;
  bf16x8 qfh[16], qfl[16];            // Q hi/lo resident (B-operand layout)
#pragma unroll
  for (int kc = 0; kc < 16; ++kc) {
    qfh[kc] = *(const bf16x8*)(Qh + qoff + kc * 16);
    qfl[kc] = *(const bf16x8*)(Ql + qoff + kc * 16);
  }
  const unsigned short* Kgh = Kh + (size_t)b * 4096 * 256;
  const unsigned short* Kgl = Kl + (size_t)b * 4096 * 256;
  const float4* Vg = Vpp + (size_t)b * 4096;
  const int r0 = t >> 5;              // staging row within 8-row group
  const int sseg = (t & 31) * 8;      // staging column segment
  float a0 = 0.f, a1 = 0.f, a2 = 0.f, al = 0.f;
  const int jt0 = jh * 64;
  {  // prologue: stage tile jt0 into buf 0
    const int jbase = jt0 * 32;
#pragma unroll
    for (int i = 0; i < 4; ++i) {
      const int row = i * 8 + r0;
      const size_t g = (size_t)(jbase + row) * 256 + sseg;
      *(bf16x8*)&Kt[0][0][row * 264 + sseg] = *(const bf16x8*)(Kgh + g);
      *(bf16x8*)&Kt[0][1][row * 264 + sseg] = *(const bf16x8*)(Kgl + g);
    }
    if (t < 32) Vt[0][t] = Vg[jbase + t];
  }
  __syncthreads();
  for (int it = 0; it < 64; ++it) {
    const int cur = it & 1, nxt = cur ^ 1;
    const bool pf = (it < 63);
    bf16x8 th[4], tl[4];
    float4 vpf = make_float4(0.f, 0.f, 0.f, 0.f);
    if (pf) {  // issue next-tile loads early; latency hides under compute
      const int jb2 = (jt0 + it + 1) * 32;
#pragma unroll
      for (int i = 0; i < 4; ++i) {
        const size_t g = (size_t)(jb2 + i * 8 + r0) * 256 + sseg;
        th[i] = *(const bf16x8*)(Kgh + g);
        tl[i] = *(const bf16x8*)(Kgl + g);
      }
      if (t < 32) vpf = Vg[jb2 + t];
    }
    // S^T[32j][32q] = K·Q^T; three accumulators = three 16-long MFMA chains
    f32x16 sA, sB, sC;
#pragma unroll
    for (int r = 0; r < 16; ++r) { sA[r] = 0.f; sB[r] = 0.f; sC[r] = 0.f; }
    const short* KH = Kt[cur][0];
    const short* KL = Kt[cur][1];
    __builtin_amdgcn_s_setprio(1);
#pragma unroll
    for (int kc = 0; kc < 16; ++kc) {
      bf16x8 kh = *(const bf16x8*)&KH[l31 * 264 + kc * 16 + half * 8];
      bf16x8 kl = *(const bf16x8*)&KL[l31 * 264 + kc * 16 + half * 8];
      sA = mfma32(kh, qfh[kc], sA);   // Kh·Qh
      sB = mfma32(kh, qfl[kc], sB);   // Kh·Ql
      sC = mfma32(kl, qfh[kc], sC);   // Kl·Qh
    }
    __builtin_amdgcn_s_setprio(0);
#pragma unroll
    for (int r = 0; r < 16; ++r) {
      const float p = __builtin_amdgcn_exp2f(sA[r] + sB[r] + sC[r]);
      const float4 vj = Vt[cur][(r & 3) + 8 * (r >> 2) + 4 * half];
      a0 += p * vj.x; a1 += p * vj.y; a2 += p * vj.z; al += p;
    }
    if (pf) {  // write prefetched tile into the buffer consumed 2 tiles ago
#pragma unroll
      for (int i = 0; i < 4; ++i) {
        const int row = i * 8 + r0;
        *(bf16x8*)&Kt[nxt][0][row * 264 + sseg] = th[i];
        *(bf16x8*)&Kt[nxt][1][row * 264 + sseg] = tl[i];
      }
      if (t < 32) Vt[nxt][t] = vpf;
    }
    __syncthreads();  // single barrier per tile
  }
  // halves hold disjoint j-sets for the same q: one swap-add finishes the sum
  a0 += __shfl_xor(a0, 32);
  a1 += __shfl_xor(a1, 32);
  a2 += __shfl_xor(a2, 32);
  al += __shfl_xor(al, 32);
  if (half == 0) {
    const int idx = b * 4096 + qrow;
    float* ps = partsum + (size_t)idx * 4;
    atomicAdd(ps + 0, a0);
    atomicAdd(ps + 1, a1);
    atomicAdd(ps + 2, a2);
    atomicAdd(ps + 3, al);
    __threadfence();
    const unsigned int old = atomicAdd(&cnt[idx], 1u);
    if (old == 1u) {   // last arriver finalizes; atomic reads are coherent
      const float s0 = atomicAdd(ps + 0, 0.f);
      const float s1 = atomicAdd(ps + 1, 0.f);
      const float s2 = atomicAdd(ps + 2, 0.f);
      const float sl = atomicAdd(ps + 3, 0.f);
      const float rl = 1.f / sl;
      out[(size_t)idx * 3 + 0] = s0 * rl + co_b[0];
      out[(size_t)idx * 3 + 1] = s1 * rl + co_b[1];
      out[(size_t)idx * 3 + 2] = s2 * rl + co_b[2];
    }
  }
}

// ---------------------------------------------------------------------------
extern "C" void kernel_launch(void* const* d_in, const int* in_sizes, int n_in,
                              void* d_out, int out_size, void* d_ws, size_t ws_size,
                              hipStream_t stream) {
  const float* x = (const float*)d_in[0];
  const float* fc1_w = (const float*)d_in[1];
  const float* fc1_b = (const float*)d_in[2];
  const float* c1q_w = (const float*)d_in[3];
  const float* c1q_b = (const float*)d_in[4];
  const float* c2q_w = (const float*)d_in[5];
  const float* c2q_b = (const float*)d_in[6];
  const float* c3q_w = (const float*)d_in[7];
  const float* c3q_b = (const float*)d_in[8];
  const float* c3k_w = (const float*)d_in[9];
  const float* c3k_b = (const float*)d_in[10];
  const float* c1v_w = (const float*)d_in[11];
  const float* c1v_b = (const float*)d_in[12];
  const float* c2v_w = (const float*)d_in[13];
  const float* c2v_b = (const float*)d_in[14];
  const float* c3v_w = (const float*)d_in[15];
  const float* c3v_b = (const float*)d_in[16];
  const float* bn1q_g = (const float*)d_in[17];
  const float* bn1q_be = (const float*)d_in[18];
  const float* bn1q_m = (const float*)d_in[19];
  const float* bn1q_v = (const float*)d_in[20];
  const float* bn2q_g = (const float*)d_in[21];
  const float* bn2q_be = (const float*)d_in[22];
  const float* bn2q_m = (const float*)d_in[23];
  const float* bn2q_v = (const float*)d_in[24];
  const float* bn1k_g = (const float*)d_in[25];
  const float* bn1k_be = (const float*)d_in[26];
  const float* bn1k_m = (const float*)d_in[27];
  const float* bn1k_v = (const float*)d_in[28];
  const float* bn2k_g = (const float*)d_in[29];
  const float* bn2k_be = (const float*)d_in[30];
  const float* bn2k_m = (const float*)d_in[31];
  const float* bn2k_v = (const float*)d_in[32];
  const float* bn1v_g = (const float*)d_in[33];
  const float* bn1v_be = (const float*)d_in[34];
  const float* bn1v_m = (const float*)d_in[35];
  const float* bn1v_v = (const float*)d_in[36];
  const float* bn2v_g = (const float*)d_in[37];
  const float* bn2v_be = (const float*)d_in[38];
  const float* bn2v_m = (const float*)d_in[39];
  const float* bn2v_v = (const float*)d_in[40];
  const float* co_w = (const float*)d_in[41];
  const float* co_b = (const float*)d_in[42];

  char* ws = (char*)d_ws;
  float* h_t = (float*)(ws + 0);                            // 1 MB [8][128][256]
  float* T1q = (float*)(ws + 1048576);                      // 512KB each
  float* T1k = (float*)(ws + 1572864);
  float* T1v = (float*)(ws + 2097152);
  unsigned short* Q2H = (unsigned short*)(ws + 2621440);    // 512KB each, [8][256][128]
  unsigned short* Q2L = (unsigned short*)(ws + 3145728);
  unsigned short* K2H = (unsigned short*)(ws + 3670016);
  unsigned short* K2L = (unsigned short*)(ws + 4194304);
  float* V2F = (float*)(ws + 4718592);                      // 1MB fp32 [8][128][256]
  unsigned short* QhB = (unsigned short*)(ws + 5767168);    // 16MB each, [8][4096][256]
  unsigned short* QlB = (unsigned short*)(ws + 22544384);
  unsigned short* KhB = (unsigned short*)(ws + 39321600);
  unsigned short* KlB = (unsigned short*)(ws + 56098816);
  float4* Vpp = (float4*)(ws + 72876032);                   // 512KB [8][4096] f4
  float* partsum = (float*)(ws + 73416704);                 // 512KB [8][4096][4] f32
  unsigned int* cnt = (unsigned int*)(ws + 73940992);       // 128KB [8][4096] u32
  // total ws usage: ~71 MB

  // zero the atomic-combine buffers (captured into the graph; runs per replay)
  hipMemsetAsync(ws + 73416704, 0, 524288 + 131072, stream);

  k_fc1<<<8192, 256, 0, stream>>>(x, fc1_w, fc1_b, h_t);
  k_conv1<<<dim3(512, 2), 256, 0, stream>>>(
      h_t, c1q_w, c1q_b, c1v_w, c1v_b,
      bn1q_g, bn1q_be, bn1q_m, bn1q_v,
      bn1k_g, bn1k_be, bn1k_m, bn1k_v,
      bn1v_g, bn1v_be, bn1v_m, bn1v_v,
      T1q, T1k, T1v);
  k_conv2<<<dim3(8, 3, 2), 256, 0, stream>>>(
      T1q, T1k, T1v, c2q_w, c2q_b, c2v_w, c2v_b,
      bn2q_g, bn2q_be, bn2q_m, bn2q_v,
      bn2k_g, bn2k_be, bn2k_m, bn2k_v,
      bn2v_g, bn2v_be, bn2v_m, bn2v_v,
      Q2H, Q2L, K2H, K2L, V2F);
  k_conv3all<<<dim3(64, 8, 3), 256, 0, stream>>>(
      c3q_w, c3q_b, c3k_w, c3k_b, Q2H, Q2L, K2H, K2L,
      QhB, QlB, KhB, KlB, c3v_w, c3v_b, V2F, co_w, Vpp);
  k_attn<<<512, 256, 0, stream>>>(QhB, QlB, KhB, KlB, Vpp, partsum, cnt,
                                  co_b, (float*)d_out);
}

// Round 7
// 676.351 us; speedup vs baseline: 1.2364x; 1.0453x over previous
//
#include <hip/hip_runtime.h>
#include <cstdint>
#include <cstddef>

#define EPS 1e-5f

typedef __attribute__((ext_vector_type(8))) short bf16x8;
typedef __attribute__((ext_vector_type(4))) float f32x4;
typedef __attribute__((ext_vector_type(16))) float f32x16;

__device__ __forceinline__ unsigned short rne_bf16(float f) {
  union { float f; unsigned int u; } v; v.f = f;
  unsigned int u = v.u;
  return (unsigned short)((u + 0x7fffu + ((u >> 16) & 1u)) >> 16);
}
__device__ __forceinline__ float bf16_to_f(unsigned short h) {
  union { unsigned int u; float f; } v; v.u = ((unsigned int)h) << 16; return v.f;
}
// split fp32 into hi/lo bf16 pair: hi+lo represents v to ~2^-17 relative
__device__ __forceinline__ void split_hl(float v, unsigned short& h, unsigned short& l) {
  h = rne_bf16(v);
  l = rne_bf16(v - bf16_to_f(h));
}
__device__ __forceinline__ f32x4 mfma16(bf16x8 a, bf16x8 b, f32x4 c) {
  return __builtin_amdgcn_mfma_f32_16x16x32_bf16(a, b, c, 0, 0, 0);
}
__device__ __forceinline__ f32x16 mfma32(bf16x8 a, bf16x8 b, f32x16 c) {
  return __builtin_amdgcn_mfma_f32_32x32x16_bf16(a, b, c, 0, 0, 0);
}

// ---------------------------------------------------------------------------
// Stage 1: fc1. h_t[b][k][m] = x[b]·fc1_w[m*128+k] + fc1_b.  One wave per row.
// HBM-bound on the 134 MB weight read (~21 us floor).
// ---------------------------------------------------------------------------
__global__ __launch_bounds__(256) void k_fc1(const float* __restrict__ x,
                                             const float* __restrict__ w,
                                             const float* __restrict__ bias,
                                             float* __restrict__ h_t) {
  const int lane = threadIdx.x & 63;
  const int wv = threadIdx.x >> 6;
  const int r = blockIdx.x * 4 + wv;               // weight row 0..32767
  const float4* wr = (const float4*)(w + (size_t)r * 1024);
  float acc[8] = {0, 0, 0, 0, 0, 0, 0, 0};
#pragma unroll
  for (int i = 0; i < 4; ++i) {
    float4 wv4 = wr[lane + i * 64];
#pragma unroll
    for (int b = 0; b < 8; ++b) {
      float4 xv = ((const float4*)(x + b * 1024))[lane + i * 64];
      acc[b] += wv4.x * xv.x + wv4.y * xv.y + wv4.z * xv.z + wv4.w * xv.w;
    }
  }
#pragma unroll
  for (int d = 1; d < 64; d <<= 1) {
#pragma unroll
    for (int b = 0; b < 8; ++b) acc[b] += __shfl_xor(acc[b], d);
  }
  if (lane == 0) {
    const int mm = r >> 7, kk = r & 127;
    const float bb = bias[r];
#pragma unroll
    for (int b = 0; b < 8; ++b) h_t[b * 32768 + kk * 256 + mm] = acc[b] + bb;
  }
}

// ---------------------------------------------------------------------------
// Stage 2a: conv1 + BN + ReLU (fp32).
// ---------------------------------------------------------------------------
__global__ __launch_bounds__(256) void k_conv1(
    const float* __restrict__ h_t,
    const float* __restrict__ c1q_w, const float* __restrict__ c1q_b,
    const float* __restrict__ c1v_w, const float* __restrict__ c1v_b,
    const float* __restrict__ g1q, const float* __restrict__ be1q,
    const float* __restrict__ mu1q, const float* __restrict__ va1q,
    const float* __restrict__ g1k, const float* __restrict__ be1k,
    const float* __restrict__ mu1k, const float* __restrict__ va1k,
    const float* __restrict__ g1v, const float* __restrict__ be1v,
    const float* __restrict__ mu1v, const float* __restrict__ va1v,
    float* __restrict__ T1q, float* __restrict__ T1k, float* __restrict__ T1v) {
  const int m = threadIdx.x;
  const int o = blockIdx.x & 63;
  const int b = blockIdx.x >> 6;
  const int path = blockIdx.y;
  const float* w = (path == 0 ? c1q_w : c1v_w) + o * 128;
  const float* h = h_t + b * 32768 + m;
  float acc = 0.f;
#pragma unroll 8
  for (int c = 0; c < 128; ++c) acc += w[c] * h[c * 256];
  if (path == 0) {
    const float z = acc + c1q_b[o];
    const float sq = g1q[o] / sqrtf(va1q[o] + EPS);
    T1q[b * 16384 + o * 256 + m] = fmaxf((z - mu1q[o]) * sq + be1q[o], 0.f);
    const float sk = g1k[o] / sqrtf(va1k[o] + EPS);
    T1k[b * 16384 + o * 256 + m] = fmaxf((z - mu1k[o]) * sk + be1k[o], 0.f);
  } else {
    const float z = acc + c1v_b[o];
    const float sv = g1v[o] / sqrtf(va1v[o] + EPS);
    T1v[b * 16384 + o * 256 + m] = fmaxf((z - mu1v[o]) * sv + be1v[o], 0.f);
  }
}

// ---------------------------------------------------------------------------
// Stage 2b: conv2 + BN + ReLU.  t[64] FULLY unrolled -> stays in VGPRs.
//   Q/K paths: output TRANSPOSED hi/lo bf16 [b][m(256)][c2(128)]
//   V path:    output fp32 V2F [b][c2(128)][m(256)]
// ---------------------------------------------------------------------------
__global__ __launch_bounds__(256) void k_conv2(
    const float* __restrict__ T1q, const float* __restrict__ T1k,
    const float* __restrict__ T1v,
    const float* __restrict__ c2q_w, const float* __restrict__ c2q_b,
    const float* __restrict__ c2v_w, const float* __restrict__ c2v_b,
    const float* __restrict__ g2q, const float* __restrict__ be2q,
    const float* __restrict__ mu2q, const float* __restrict__ va2q,
    const float* __restrict__ g2k, const float* __restrict__ be2k,
    const float* __restrict__ mu2k, const float* __restrict__ va2k,
    const float* __restrict__ g2v, const float* __restrict__ be2v,
    const float* __restrict__ mu2v, const float* __restrict__ va2v,
    unsigned short* __restrict__ Q2H, unsigned short* __restrict__ Q2L,
    unsigned short* __restrict__ K2H, unsigned short* __restrict__ K2L,
    float* __restrict__ V2F) {
  const int m = threadIdx.x;
  const int b = blockIdx.x;
  const int path = blockIdx.y;
  const int oc = blockIdx.z;
  const float* T1 = (path == 0 ? T1q : path == 1 ? T1k : T1v) + b * 16384 + m;
  const float* w = (path == 2 ? c2v_w : c2q_w);
  const float* cb = (path == 2 ? c2v_b : c2q_b);
  const float* g = (path == 0 ? g2q : path == 1 ? g2k : g2v);
  const float* be = (path == 0 ? be2q : path == 1 ? be2k : be2v);
  const float* mu = (path == 0 ? mu2q : path == 1 ? mu2k : mu2v);
  const float* va = (path == 0 ? va2q : path == 1 ? va2k : va2v);
  float t[64];
#pragma unroll
  for (int c = 0; c < 64; ++c) t[c] = T1[c * 256];
  unsigned short* oh =
      (path == 0 ? Q2H : K2H) + b * 32768 + m * 128 + oc * 64;
  unsigned short* ol =
      (path == 0 ? Q2L : K2L) + b * 32768 + m * 128 + oc * 64;
  for (int og = 0; og < 8; ++og) {
    bf16x8 ph, pl;
#pragma unroll
    for (int j = 0; j < 8; ++j) {
      const int o = oc * 64 + og * 8 + j;
      float acc = cb[o];
      const float* wo = w + o * 64;
#pragma unroll
      for (int c = 0; c < 64; ++c) acc += wo[c] * t[c];
      const float s = g[o] / sqrtf(va[o] + EPS);
      const float val = fmaxf((acc - mu[o]) * s + be[o], 0.f);
      if (path == 2) {
        V2F[b * 32768 + o * 256 + m] = val;
      } else {
        unsigned short hh, ll;
        split_hl(val, hh, ll);
        ph[j] = (short)hh; pl[j] = (short)ll;
      }
    }
    if (path != 2) {
      *(bf16x8*)(oh + og * 8) = ph;
      *(bf16x8*)(ol + og * 8) = pl;
    }
  }
}

// ---------------------------------------------------------------------------
// Stage 3 merged: z=0 -> conv3-Q (scale folds 1/sqrt(128)*log2(e) for the
// exp2 softmax), z=1 -> conv3-K, z=2 (x<16) -> U + Vpp (co_w-projected V).
// ---------------------------------------------------------------------------
__global__ __launch_bounds__(256) void k_conv3all(
    const float* __restrict__ c3q_w, const float* __restrict__ c3q_b,
    const float* __restrict__ c3k_w, const float* __restrict__ c3k_b,
    const unsigned short* __restrict__ Q2H, const unsigned short* __restrict__ Q2L,
    const unsigned short* __restrict__ K2H, const unsigned short* __restrict__ K2L,
    unsigned short* __restrict__ QhB, unsigned short* __restrict__ QlB,
    unsigned short* __restrict__ KhB, unsigned short* __restrict__ KlB,
    const float* __restrict__ c3v_w, const float* __restrict__ c3v_b,
    const float* __restrict__ V2F, const float* __restrict__ co_w,
    float4* __restrict__ Vpp) {
  const int z = blockIdx.z;
  const int b = blockIdx.y;
  if (z == 2) {
    if (blockIdx.x >= 16) return;
    __shared__ float Us[387];
    __shared__ float Up[256][3];
    const int tt = threadIdx.x;
    {  // U[c][o] = sum_m V2F[b][c][m]*co_w[o][m]; pair-split over m halves
      const int c = tt >> 1, mh = tt & 1;
      const float* v = V2F + b * 32768 + c * 256 + mh * 128;
      const float* cw0 = co_w + mh * 128;
      float u0 = 0.f, u1 = 0.f, u2 = 0.f;
#pragma unroll 4
      for (int mm = 0; mm < 128; ++mm) {
        const float xv = v[mm];
        u0 += xv * cw0[mm];
        u1 += xv * cw0[256 + mm];
        u2 += xv * cw0[512 + mm];
      }
      Up[tt][0] = u0; Up[tt][1] = u1; Up[tt][2] = u2;
      if (tt < 3) {  // col-sums of co_w (for the bias term)
        float s = 0.f;
        for (int mm = 0; mm < 256; ++mm) s += co_w[tt * 256 + mm];
        Us[384 + tt] = s;
      }
    }
    __syncthreads();
    if ((tt & 1) == 0) {
      const int c = tt >> 1;
      Us[c * 3 + 0] = Up[tt][0] + Up[tt + 1][0];
      Us[c * 3 + 1] = Up[tt][1] + Up[tt + 1][1];
      Us[c * 3 + 2] = Up[tt][2] + Up[tt + 1][2];
    }
    __syncthreads();
    const int n = blockIdx.x * 256 + tt;
    const float* w = c3v_w + (size_t)n * 128;
    float a0 = 0.f, a1 = 0.f, a2 = 0.f;
#pragma unroll 4
    for (int c = 0; c < 128; ++c) {
      const float wc = w[c];
      a0 += wc * Us[c * 3 + 0];
      a1 += wc * Us[c * 3 + 1];
      a2 += wc * Us[c * 3 + 2];
    }
    const float bb = c3v_b[n];
    Vpp[(size_t)b * 4096 + n] =
        make_float4(a0 + bb * Us[384], a1 + bb * Us[385], a2 + bb * Us[386], 0.f);
    return;
  }
  // z=0: Q, z=1: K — split-MFMA conv3, output hi/lo bf16 pair Y[b][n][m]
  const float* W = (z == 0) ? c3q_w : c3k_w;
  const float* bias = (z == 0) ? c3q_b : c3k_b;
  const unsigned short* Xh = (z == 0) ? Q2H : K2H;
  const unsigned short* Xl = (z == 0) ? Q2L : K2L;
  unsigned short* Yh = (z == 0) ? QhB : KhB;
  unsigned short* Yl = (z == 0) ? QlB : KlB;
  const float scale = (z == 0) ? 0.08838834764831845f * 1.4426950408889634f : 1.0f;
  const int lane = threadIdx.x & 63, wv = threadIdx.x >> 6;
  const int l15 = lane & 15, quad = lane >> 4;
  const unsigned short* XH = Xh + b * 32768;
  const unsigned short* XL = Xl + b * 32768;
  unsigned short* YH = Yh + (size_t)b * 4096 * 256;
  unsigned short* YL = Yl + (size_t)b * 4096 * 256;
  const int nb = blockIdx.x * 64 + wv * 16;
  const float* wr = W + (size_t)(nb + l15) * 128 + quad * 8;
  bf16x8 ah[4], al[4];
#pragma unroll
  for (int ks = 0; ks < 4; ++ks) {
#pragma unroll
    for (int j = 0; j < 8; ++j) {
      unsigned short hh, ll;
      split_hl(wr[ks * 32 + j], hh, ll);
      ah[ks][j] = (short)hh; al[ks][j] = (short)ll;
    }
  }
  f32x4 acc[16];
#pragma unroll
  for (int ms = 0; ms < 16; ++ms) acc[ms] = (f32x4){0, 0, 0, 0};
#pragma unroll
  for (int ks = 0; ks < 4; ++ks) {
#pragma unroll
    for (int ms = 0; ms < 16; ++ms) {
      const size_t off = (size_t)(ms * 16 + l15) * 128 + ks * 32 + quad * 8;
      bf16x8 bh = *(const bf16x8*)(XH + off);
      bf16x8 bl = *(const bf16x8*)(XL + off);
      acc[ms] = mfma16(ah[ks], bh, acc[ms]);
      acc[ms] = mfma16(al[ks], bh, acc[ms]);
      acc[ms] = mfma16(ah[ks], bl, acc[ms]);
    }
  }
#pragma unroll
  for (int r = 0; r < 4; ++r) {
    const int n = nb + quad * 4 + r;
    const float bv = bias[n];
#pragma unroll
    for (int ms = 0; ms < 16; ++ms) {
      const float v = (acc[ms][r] + bv) * scale;
      unsigned short hh, ll;
      split_hl(v, hh, ll);
      YH[(size_t)n * 256 + ms * 16 + l15] = hh;
      YL[(size_t)n * 256 + ms * 16 + l15] = ll;
    }
  }
}

// ---------------------------------------------------------------------------
// Stage 4: attention.  LDS-read-BW was the bottleneck (r6: 8 waves/CU x 48
// ds_read_b128/tile x ~12cyc ~= 4600 cyc/tile >> 768 MFMA cyc; MfmaUtil 34%
// matches).  Fix: 64 q-rows per wave (TWO MFMA B-sets) -> each kh/kl LDS read
// feeds 6 MFMAs instead of 3; per-CU LDS reads halve.  Costs ~400 VGPR ->
// 1 block/CU (launch_bounds(256,1): 512-VGPR budget, no spill).  Single LDS
// buffer (34 KB) + register prefetch of next tile issued BEFORE compute.
// Grid 256 = 8b x 16qt x 2jh; b=bid&7 pins each batch's 4MB K to one XCD L2.
// Combine fused via device-scope atomics (2 contributors per q-row).
// ---------------------------------------------------------------------------
__global__ __launch_bounds__(256, 1) void k_attn(
    const unsigned short* __restrict__ Qh, const unsigned short* __restrict__ Ql,
    const unsigned short* __restrict__ Kh, const unsigned short* __restrict__ Kl,
    const float4* __restrict__ Vpp, float* __restrict__ partsum,
    unsigned int* __restrict__ cnt, const float* __restrict__ co_b,
    float* __restrict__ out) {
  __shared__ __align__(16) short Kth[32 * 264];   // K hi tile [32][256] pad 264
  __shared__ __align__(16) short Ktl[32 * 264];   // K lo tile
  __shared__ __align__(16) float4 Vt[32];         // projected V tile
  const int t = threadIdx.x;
  const int lane = t & 63, wv = t >> 6;
  const int l31 = lane & 31, half = lane >> 5;
  const int b = blockIdx.x & 7;        // batch pinned per-XCD (bid%8 = XCD)
  const int qt = (blockIdx.x >> 3) & 15;
  const int jh = blockIdx.x >> 7;      // j-half 0/1
  const int qbase = qt * 256 + wv * 64;
  const size_t qoff0 = ((size_t)b * 4096 + qbase + l31) * 256 + half * 8;
  const size_t qoff1 = qoff0 + 32 * 256;
  bf16x8 qh0[16], ql0[16], qh1[16], ql1[16];   // 2 B-sets of Q hi/lo resident
#pragma unroll
  for (int kc = 0; kc < 16; ++kc) {
    qh0[kc] = *(const bf16x8*)(Qh + qoff0 + kc * 16);
    ql0[kc] = *(const bf16x8*)(Ql + qoff0 + kc * 16);
    qh1[kc] = *(const bf16x8*)(Qh + qoff1 + kc * 16);
    ql1[kc] = *(const bf16x8*)(Ql + qoff1 + kc * 16);
  }
  const unsigned short* Kgh = Kh + (size_t)b * 4096 * 256;
  const unsigned short* Kgl = Kl + (size_t)b * 4096 * 256;
  const float4* Vg = Vpp + (size_t)b * 4096;
  const int rr = t >> 5;              // staging row within 8-row group
  const int sseg = (t & 31) * 8;      // staging column segment
  float a00 = 0.f, a01 = 0.f, a02 = 0.f, a0l = 0.f;
  float a10 = 0.f, a11 = 0.f, a12 = 0.f, a1l = 0.f;
  const int jrow0 = jh * 2048;
  {  // prologue: stage tile 0
#pragma unroll
    for (int i = 0; i < 4; ++i) {
      const int row = i * 8 + rr;
      const size_t g = (size_t)(jrow0 + row) * 256 + sseg;
      *(bf16x8*)&Kth[row * 264 + sseg] = *(const bf16x8*)(Kgh + g);
      *(bf16x8*)&Ktl[row * 264 + sseg] = *(const bf16x8*)(Kgl + g);
    }
    if (t < 32) Vt[t] = Vg[jrow0 + t];
  }
  __syncthreads();
  for (int it = 0; it < 64; ++it) {
    const bool pf = (it < 63);
    bf16x8 th[4], tl[4];
    float4 vpf = make_float4(0.f, 0.f, 0.f, 0.f);
    if (pf) {  // issue next-tile loads BEFORE compute; latency hides under it
      const int jb2 = jrow0 + (it + 1) * 32;
#pragma unroll
      for (int i = 0; i < 4; ++i) {
        const size_t g = (size_t)(jb2 + i * 8 + rr) * 256 + sseg;
        th[i] = *(const bf16x8*)(Kgh + g);
        tl[i] = *(const bf16x8*)(Kgl + g);
      }
      if (t < 32) vpf = Vg[jb2 + t];
    }
    // S^T = K·Q^T for both q-sets: 6 independent 16-long MFMA chains,
    // each kh/kl LDS read feeds 6 MFMAs (2x intensity vs r6).
    f32x16 sA0, sB0, sC0, sA1, sB1, sC1;
#pragma unroll
    for (int r = 0; r < 16; ++r) {
      sA0[r] = 0.f; sB0[r] = 0.f; sC0[r] = 0.f;
      sA1[r] = 0.f; sB1[r] = 0.f; sC1[r] = 0.f;
    }
#pragma unroll
    for (int kc = 0; kc < 16; ++kc) {
      bf16x8 kh = *(const bf16x8*)&Kth[l31 * 264 + kc * 16 + half * 8];
      bf16x8 kl = *(const bf16x8*)&Ktl[l31 * 264 + kc * 16 + half * 8];
      sA0 = mfma32(kh, qh0[kc], sA0);
      sA1 = mfma32(kh, qh1[kc], sA1);
      sB0 = mfma32(kh, ql0[kc], sB0);
      sB1 = mfma32(kh, ql1[kc], sB1);
      sC0 = mfma32(kl, qh0[kc], sC0);
      sC1 = mfma32(kl, qh1[kc], sC1);
    }
#pragma unroll
    for (int r = 0; r < 16; ++r) {
      const float4 vj = Vt[(r & 3) + 8 * (r >> 2) + 4 * half];
      const float p0 = __builtin_amdgcn_exp2f(sA0[r] + sB0[r] + sC0[r]);
      const float p1 = __builtin_amdgcn_exp2f(sA1[r] + sB1[r] + sC1[r]);
      a00 += p0 * vj.x; a01 += p0 * vj.y; a02 += p0 * vj.z; a0l += p0;
      a10 += p1 * vj.x; a11 += p1 * vj.y; a12 += p1 * vj.z; a1l += p1;
    }
    __syncthreads();                  // all waves done reading the tile
    if (pf) {                         // write prefetched tile into LDS
#pragma unroll
      for (int i = 0; i < 4; ++i) {
        const int row = i * 8 + rr;
        *(bf16x8*)&Kth[row * 264 + sseg] = th[i];
        *(bf16x8*)&Ktl[row * 264 + sseg] = tl[i];
      }
      if (t < 32) Vt[t] = vpf;
    }
    __syncthreads();                  // writes visible
  }
  // halves hold disjoint j-sets for the same q: one swap-add finishes the sum
  a00 += __shfl_xor(a00, 32); a01 += __shfl_xor(a01, 32);
  a02 += __shfl_xor(a02, 32); a0l += __shfl_xor(a0l, 32);
  a10 += __shfl_xor(a10, 32); a11 += __shfl_xor(a11, 32);
  a12 += __shfl_xor(a12, 32); a1l += __shfl_xor(a1l, 32);
  if (half == 0) {
#pragma unroll
    for (int s = 0; s < 2; ++s) {
      const float v0 = s ? a10 : a00, v1 = s ? a11 : a01;
      const float v2 = s ? a12 : a02, vl = s ? a1l : a0l;
      const int idx = b * 4096 + qbase + s * 32 + l31;
      float* ps = partsum + (size_t)idx * 4;
      atomicAdd(ps + 0, v0);
      atomicAdd(ps + 1, v1);
      atomicAdd(ps + 2, v2);
      atomicAdd(ps + 3, vl);
      __threadfence();
      const unsigned int old = atomicAdd(&cnt[idx], 1u);
      if (old == 1u) {  // last arriver finalizes; atomic reads are coherent
        const float s0 = atomicAdd(ps + 0, 0.f);
        const float s1 = atomicAdd(ps + 1, 0.f);
        const float s2 = atomicAdd(ps + 2, 0.f);
        const float sl = atomicAdd(ps + 3, 0.f);
        const float rl = 1.f / sl;
        out[(size_t)idx * 3 + 0] = s0 * rl + co_b[0];
        out[(size_t)idx * 3 + 1] = s1 * rl + co_b[1];
        out[(size_t)idx * 3 + 2] = s2 * rl + co_b[2];
      }
    }
  }
}

// ---------------------------------------------------------------------------
extern "C" void kernel_launch(void* const* d_in, const int* in_sizes, int n_in,
                              void* d_out, int out_size, void* d_ws, size_t ws_size,
                              hipStream_t stream) {
  const float* x = (const float*)d_in[0];
  const float* fc1_w = (const float*)d_in[1];
  const float* fc1_b = (const float*)d_in[2];
  const float* c1q_w = (const float*)d_in[3];
  const float* c1q_b = (const float*)d_in[4];
  const float* c2q_w = (const float*)d_in[5];
  const float* c2q_b = (const float*)d_in[6];
  const float* c3q_w = (const float*)d_in[7];
  const float* c3q_b = (const float*)d_in[8];
  const float* c3k_w = (const float*)d_in[9];
  const float* c3k_b = (const float*)d_in[10];
  const float* c1v_w = (const float*)d_in[11];
  const float* c1v_b = (const float*)d_in[12];
  const float* c2v_w = (const float*)d_in[13];
  const float* c2v_b = (const float*)d_in[14];
  const float* c3v_w = (const float*)d_in[15];
  const float* c3v_b = (const float*)d_in[16];
  const float* bn1q_g = (const float*)d_in[17];
  const float* bn1q_be = (const float*)d_in[18];
  const float* bn1q_m = (const float*)d_in[19];
  const float* bn1q_v = (const float*)d_in[20];
  const float* bn2q_g = (const float*)d_in[21];
  const float* bn2q_be = (const float*)d_in[22];
  const float* bn2q_m = (const float*)d_in[23];
  const float* bn2q_v = (const float*)d_in[24];
  const float* bn1k_g = (const float*)d_in[25];
  const float* bn1k_be = (const float*)d_in[26];
  const float* bn1k_m = (const float*)d_in[27];
  const float* bn1k_v = (const float*)d_in[28];
  const float* bn2k_g = (const float*)d_in[29];
  const float* bn2k_be = (const float*)d_in[30];
  const float* bn2k_m = (const float*)d_in[31];
  const float* bn2k_v = (const float*)d_in[32];
  const float* bn1v_g = (const float*)d_in[33];
  const float* bn1v_be = (const float*)d_in[34];
  const float* bn1v_m = (const float*)d_in[35];
  const float* bn1v_v = (const float*)d_in[36];
  const float* bn2v_g = (const float*)d_in[37];
  const float* bn2v_be = (const float*)d_in[38];
  const float* bn2v_m = (const float*)d_in[39];
  const float* bn2v_v = (const float*)d_in[40];
  const float* co_w = (const float*)d_in[41];
  const float* co_b = (const float*)d_in[42];

  char* ws = (char*)d_ws;
  float* h_t = (float*)(ws + 0);                            // 1 MB [8][128][256]
  float* T1q = (float*)(ws + 1048576);                      // 512KB each
  float* T1k = (float*)(ws + 1572864);
  float* T1v = (float*)(ws + 2097152);
  unsigned short* Q2H = (unsigned short*)(ws + 2621440);    // 512KB each, [8][256][128]
  unsigned short* Q2L = (unsigned short*)(ws + 3145728);
  unsigned short* K2H = (unsigned short*)(ws + 3670016);
  unsigned short* K2L = (unsigned short*)(ws + 4194304);
  float* V2F = (float*)(ws + 4718592);                      // 1MB fp32 [8][128][256]
  unsigned short* QhB = (unsigned short*)(ws + 5767168);    // 16MB each, [8][4096][256]
  unsigned short* QlB = (unsigned short*)(ws + 22544384);
  unsigned short* KhB = (unsigned short*)(ws + 39321600);
  unsigned short* KlB = (unsigned short*)(ws + 56098816);
  float4* Vpp = (float4*)(ws + 72876032);                   // 512KB [8][4096] f4
  float* partsum = (float*)(ws + 73416704);                 // 512KB [8][4096][4] f32
  unsigned int* cnt = (unsigned int*)(ws + 73940992);       // 128KB [8][4096] u32
  // total ws usage: ~71 MB

  // zero the atomic-combine buffers (captured into the graph; runs per replay)
  hipMemsetAsync(ws + 73416704, 0, 524288 + 131072, stream);

  k_fc1<<<8192, 256, 0, stream>>>(x, fc1_w, fc1_b, h_t);
  k_conv1<<<dim3(512, 2), 256, 0, stream>>>(
      h_t, c1q_w, c1q_b, c1v_w, c1v_b,
      bn1q_g, bn1q_be, bn1q_m, bn1q_v,
      bn1k_g, bn1k_be, bn1k_m, bn1k_v,
      bn1v_g, bn1v_be, bn1v_m, bn1v_v,
      T1q, T1k, T1v);
  k_conv2<<<dim3(8, 3, 2), 256, 0, stream>>>(
      T1q, T1k, T1v, c2q_w, c2q_b, c2v_w, c2v_b,
      bn2q_g, bn2q_be, bn2q_m, bn2q_v,
      bn2k_g, bn2k_be, bn2k_m, bn2k_v,
      bn2v_g, bn2v_be, bn2v_m, bn2v_v,
      Q2H, Q2L, K2H, K2L, V2F);
  k_conv3all<<<dim3(64, 8, 3), 256, 0, stream>>>(
      c3q_w, c3q_b, c3k_w, c3k_b, Q2H, Q2L, K2H, K2L,
      QhB, QlB, KhB, KlB, c3v_w, c3v_b, V2F, co_w, Vpp);
  k_attn<<<256, 256, 0, stream>>>(QhB, QlB, KhB, KlB, Vpp, partsum, cnt,
                                  co_b, (float*)d_out);
}

// Round 8
// 640.406 us; speedup vs baseline: 1.3058x; 1.0561x over previous
//
#include <hip/hip_runtime.h>
#include <cstdint>
#include <cstddef>

#define EPS 1e-5f

typedef __attribute__((ext_vector_type(8))) short bf16x8;
typedef __attribute__((ext_vector_type(4))) float f32x4;
typedef __attribute__((ext_vector_type(16))) float f32x16;

__device__ __forceinline__ unsigned short rne_bf16(float f) {
  union { float f; unsigned int u; } v; v.f = f;
  unsigned int u = v.u;
  return (unsigned short)((u + 0x7fffu + ((u >> 16) & 1u)) >> 16);
}
__device__ __forceinline__ float bf16_to_f(unsigned short h) {
  union { unsigned int u; float f; } v; v.u = ((unsigned int)h) << 16; return v.f;
}
// split fp32 into hi/lo bf16 pair: hi+lo represents v to ~2^-17 relative
__device__ __forceinline__ void split_hl(float v, unsigned short& h, unsigned short& l) {
  h = rne_bf16(v);
  l = rne_bf16(v - bf16_to_f(h));
}
__device__ __forceinline__ f32x4 mfma16(bf16x8 a, bf16x8 b, f32x4 c) {
  return __builtin_amdgcn_mfma_f32_16x16x32_bf16(a, b, c, 0, 0, 0);
}
__device__ __forceinline__ f32x16 mfma32(bf16x8 a, bf16x8 b, f32x16 c) {
  return __builtin_amdgcn_mfma_f32_32x32x16_bf16(a, b, c, 0, 0, 0);
}

// ---------------------------------------------------------------------------
// Stage 1: fc1. h_t[b][k][m] = x[b]·fc1_w[m*128+k] + fc1_b.  One wave per row.
// HBM-bound on the 134 MB weight read (~21 us floor).
// ---------------------------------------------------------------------------
__global__ __launch_bounds__(256) void k_fc1(const float* __restrict__ x,
                                             const float* __restrict__ w,
                                             const float* __restrict__ bias,
                                             float* __restrict__ h_t) {
  const int lane = threadIdx.x & 63;
  const int wv = threadIdx.x >> 6;
  const int r = blockIdx.x * 4 + wv;               // weight row 0..32767
  const float4* wr = (const float4*)(w + (size_t)r * 1024);
  float acc[8] = {0, 0, 0, 0, 0, 0, 0, 0};
#pragma unroll
  for (int i = 0; i < 4; ++i) {
    float4 wv4 = wr[lane + i * 64];
#pragma unroll
    for (int b = 0; b < 8; ++b) {
      float4 xv = ((const float4*)(x + b * 1024))[lane + i * 64];
      acc[b] += wv4.x * xv.x + wv4.y * xv.y + wv4.z * xv.z + wv4.w * xv.w;
    }
  }
#pragma unroll
  for (int d = 1; d < 64; d <<= 1) {
#pragma unroll
    for (int b = 0; b < 8; ++b) acc[b] += __shfl_xor(acc[b], d);
  }
  if (lane == 0) {
    const int mm = r >> 7, kk = r & 127;
    const float bb = bias[r];
#pragma unroll
    for (int b = 0; b < 8; ++b) h_t[b * 32768 + kk * 256 + mm] = acc[b] + bb;
  }
}

// ---------------------------------------------------------------------------
// Stage 2a: conv1 + BN + ReLU (fp32).
// ---------------------------------------------------------------------------
__global__ __launch_bounds__(256) void k_conv1(
    const float* __restrict__ h_t,
    const float* __restrict__ c1q_w, const float* __restrict__ c1q_b,
    const float* __restrict__ c1v_w, const float* __restrict__ c1v_b,
    const float* __restrict__ g1q, const float* __restrict__ be1q,
    const float* __restrict__ mu1q, const float* __restrict__ va1q,
    const float* __restrict__ g1k, const float* __restrict__ be1k,
    const float* __restrict__ mu1k, const float* __restrict__ va1k,
    const float* __restrict__ g1v, const float* __restrict__ be1v,
    const float* __restrict__ mu1v, const float* __restrict__ va1v,
    float* __restrict__ T1q, float* __restrict__ T1k, float* __restrict__ T1v) {
  const int m = threadIdx.x;
  const int o = blockIdx.x & 63;
  const int b = blockIdx.x >> 6;
  const int path = blockIdx.y;
  const float* w = (path == 0 ? c1q_w : c1v_w) + o * 128;
  const float* h = h_t + b * 32768 + m;
  float acc = 0.f;
#pragma unroll 8
  for (int c = 0; c < 128; ++c) acc += w[c] * h[c * 256];
  if (path == 0) {
    const float z = acc + c1q_b[o];
    const float sq = g1q[o] / sqrtf(va1q[o] + EPS);
    T1q[b * 16384 + o * 256 + m] = fmaxf((z - mu1q[o]) * sq + be1q[o], 0.f);
    const float sk = g1k[o] / sqrtf(va1k[o] + EPS);
    T1k[b * 16384 + o * 256 + m] = fmaxf((z - mu1k[o]) * sk + be1k[o], 0.f);
  } else {
    const float z = acc + c1v_b[o];
    const float sv = g1v[o] / sqrtf(va1v[o] + EPS);
    T1v[b * 16384 + o * 256 + m] = fmaxf((z - mu1v[o]) * sv + be1v[o], 0.f);
  }
}

// ---------------------------------------------------------------------------
// Stage 2b: conv2 + BN + ReLU.  Grid (8,3,8): 192 blocks (was 48 = 19% of
// CUs), 16 outputs/thread.  t[64] fully unrolled -> VGPRs.
//   Q/K paths: output TRANSPOSED hi/lo bf16 [b][m(256)][c2(128)]
//   V path:    output fp32 V2F [b][c2(128)][m(256)]
// ---------------------------------------------------------------------------
__global__ __launch_bounds__(256) void k_conv2(
    const float* __restrict__ T1q, const float* __restrict__ T1k,
    const float* __restrict__ T1v,
    const float* __restrict__ c2q_w, const float* __restrict__ c2q_b,
    const float* __restrict__ c2v_w, const float* __restrict__ c2v_b,
    const float* __restrict__ g2q, const float* __restrict__ be2q,
    const float* __restrict__ mu2q, const float* __restrict__ va2q,
    const float* __restrict__ g2k, const float* __restrict__ be2k,
    const float* __restrict__ mu2k, const float* __restrict__ va2k,
    const float* __restrict__ g2v, const float* __restrict__ be2v,
    const float* __restrict__ mu2v, const float* __restrict__ va2v,
    unsigned short* __restrict__ Q2H, unsigned short* __restrict__ Q2L,
    unsigned short* __restrict__ K2H, unsigned short* __restrict__ K2L,
    float* __restrict__ V2F) {
  const int m = threadIdx.x;
  const int b = blockIdx.x;
  const int path = blockIdx.y;
  const int oc = blockIdx.z;          // 0..7, 16 outputs each
  const float* T1 = (path == 0 ? T1q : path == 1 ? T1k : T1v) + b * 16384 + m;
  const float* w = (path == 2 ? c2v_w : c2q_w);
  const float* cb = (path == 2 ? c2v_b : c2q_b);
  const float* g = (path == 0 ? g2q : path == 1 ? g2k : g2v);
  const float* be = (path == 0 ? be2q : path == 1 ? be2k : be2v);
  const float* mu = (path == 0 ? mu2q : path == 1 ? mu2k : mu2v);
  const float* va = (path == 0 ? va2q : path == 1 ? va2k : va2v);
  float t[64];
#pragma unroll
  for (int c = 0; c < 64; ++c) t[c] = T1[c * 256];
  unsigned short* oh =
      (path == 0 ? Q2H : K2H) + b * 32768 + m * 128 + oc * 16;
  unsigned short* ol =
      (path == 0 ? Q2L : K2L) + b * 32768 + m * 128 + oc * 16;
  for (int og = 0; og < 2; ++og) {
    bf16x8 ph, pl;
#pragma unroll
    for (int j = 0; j < 8; ++j) {
      const int o = oc * 16 + og * 8 + j;
      float acc = cb[o];
      const float* wo = w + o * 64;
#pragma unroll
      for (int c = 0; c < 64; ++c) acc += wo[c] * t[c];
      const float s = g[o] / sqrtf(va[o] + EPS);
      const float val = fmaxf((acc - mu[o]) * s + be[o], 0.f);
      if (path == 2) {
        V2F[b * 32768 + o * 256 + m] = val;
      } else {
        unsigned short hh, ll;
        split_hl(val, hh, ll);
        ph[j] = (short)hh; pl[j] = (short)ll;
      }
    }
    if (path != 2) {
      *(bf16x8*)(oh + og * 8) = ph;
      *(bf16x8*)(ol + og * 8) = pl;
    }
  }
}

// ---------------------------------------------------------------------------
// Stage 3 merged: z=0 -> conv3-Q (scale folds 1/sqrt(128)*log2(e) for the
// exp2 softmax), z=1 -> conv3-K, z=2 (x<16) -> U + Vpp (co_w-projected V).
// ---------------------------------------------------------------------------
__global__ __launch_bounds__(256) void k_conv3all(
    const float* __restrict__ c3q_w, const float* __restrict__ c3q_b,
    const float* __restrict__ c3k_w, const float* __restrict__ c3k_b,
    const unsigned short* __restrict__ Q2H, const unsigned short* __restrict__ Q2L,
    const unsigned short* __restrict__ K2H, const unsigned short* __restrict__ K2L,
    unsigned short* __restrict__ QhB, unsigned short* __restrict__ QlB,
    unsigned short* __restrict__ KhB, unsigned short* __restrict__ KlB,
    const float* __restrict__ c3v_w, const float* __restrict__ c3v_b,
    const float* __restrict__ V2F, const float* __restrict__ co_w,
    float4* __restrict__ Vpp) {
  const int z = blockIdx.z;
  const int b = blockIdx.y;
  if (z == 2) {
    if (blockIdx.x >= 16) return;
    __shared__ float Us[387];
    __shared__ float Up[256][3];
    const int tt = threadIdx.x;
    {  // U[c][o] = sum_m V2F[b][c][m]*co_w[o][m]; pair-split over m halves
      const int c = tt >> 1, mh = tt & 1;
      const float* v = V2F + b * 32768 + c * 256 + mh * 128;
      const float* cw0 = co_w + mh * 128;
      float u0 = 0.f, u1 = 0.f, u2 = 0.f;
#pragma unroll 4
      for (int mm = 0; mm < 128; ++mm) {
        const float xv = v[mm];
        u0 += xv * cw0[mm];
        u1 += xv * cw0[256 + mm];
        u2 += xv * cw0[512 + mm];
      }
      Up[tt][0] = u0; Up[tt][1] = u1; Up[tt][2] = u2;
      if (tt < 3) {  // col-sums of co_w (for the bias term)
        float s = 0.f;
        for (int mm = 0; mm < 256; ++mm) s += co_w[tt * 256 + mm];
        Us[384 + tt] = s;
      }
    }
    __syncthreads();
    if ((tt & 1) == 0) {
      const int c = tt >> 1;
      Us[c * 3 + 0] = Up[tt][0] + Up[tt + 1][0];
      Us[c * 3 + 1] = Up[tt][1] + Up[tt + 1][1];
      Us[c * 3 + 2] = Up[tt][2] + Up[tt + 1][2];
    }
    __syncthreads();
    const int n = blockIdx.x * 256 + tt;
    const float* w = c3v_w + (size_t)n * 128;
    float a0 = 0.f, a1 = 0.f, a2 = 0.f;
#pragma unroll 4
    for (int c = 0; c < 128; ++c) {
      const float wc = w[c];
      a0 += wc * Us[c * 3 + 0];
      a1 += wc * Us[c * 3 + 1];
      a2 += wc * Us[c * 3 + 2];
    }
    const float bb = c3v_b[n];
    Vpp[(size_t)b * 4096 + n] =
        make_float4(a0 + bb * Us[384], a1 + bb * Us[385], a2 + bb * Us[386], 0.f);
    return;
  }
  // z=0: Q, z=1: K — split-MFMA conv3, output hi/lo bf16 pair Y[b][n][m]
  const float* W = (z == 0) ? c3q_w : c3k_w;
  const float* bias = (z == 0) ? c3q_b : c3k_b;
  const unsigned short* Xh = (z == 0) ? Q2H : K2H;
  const unsigned short* Xl = (z == 0) ? Q2L : K2L;
  unsigned short* Yh = (z == 0) ? QhB : KhB;
  unsigned short* Yl = (z == 0) ? QlB : KlB;
  const float scale = (z == 0) ? 0.08838834764831845f * 1.4426950408889634f : 1.0f;
  const int lane = threadIdx.x & 63, wv = threadIdx.x >> 6;
  const int l15 = lane & 15, quad = lane >> 4;
  const unsigned short* XH = Xh + b * 32768;
  const unsigned short* XL = Xl + b * 32768;
  unsigned short* YH = Yh + (size_t)b * 4096 * 256;
  unsigned short* YL = Yl + (size_t)b * 4096 * 256;
  const int nb = blockIdx.x * 64 + wv * 16;
  const float* wr = W + (size_t)(nb + l15) * 128 + quad * 8;
  bf16x8 ah[4], al[4];
#pragma unroll
  for (int ks = 0; ks < 4; ++ks) {
#pragma unroll
    for (int j = 0; j < 8; ++j) {
      unsigned short hh, ll;
      split_hl(wr[ks * 32 + j], hh, ll);
      ah[ks][j] = (short)hh; al[ks][j] = (short)ll;
    }
  }
  f32x4 acc[16];
#pragma unroll
  for (int ms = 0; ms < 16; ++ms) acc[ms] = (f32x4){0, 0, 0, 0};
#pragma unroll
  for (int ks = 0; ks < 4; ++ks) {
#pragma unroll
    for (int ms = 0; ms < 16; ++ms) {
      const size_t off = (size_t)(ms * 16 + l15) * 128 + ks * 32 + quad * 8;
      bf16x8 bh = *(const bf16x8*)(XH + off);
      bf16x8 bl = *(const bf16x8*)(XL + off);
      acc[ms] = mfma16(ah[ks], bh, acc[ms]);
      acc[ms] = mfma16(al[ks], bh, acc[ms]);
      acc[ms] = mfma16(ah[ks], bl, acc[ms]);
    }
  }
#pragma unroll
  for (int r = 0; r < 4; ++r) {
    const int n = nb + quad * 4 + r;
    const float bv = bias[n];
#pragma unroll
    for (int ms = 0; ms < 16; ++ms) {
      const float v = (acc[ms][r] + bv) * scale;
      unsigned short hh, ll;
      split_hl(v, hh, ll);
      YH[(size_t)n * 256 + ms * 16 + l15] = hh;
      YL[(size_t)n * 256 + ms * 16 + l15] = ll;
    }
  }
}

// ---------------------------------------------------------------------------
// Stage 4: attention — the empirically-optimal r3 structure (32 q-rows/wave,
// double-buffered K tiles, 1 barrier/tile, 2 blocks/CU) + 3-accumulator MFMA
// chain split (16-long chains), NO setprio (m190: negative in barrier-locked
// loops; r6 regression), combine fused via device-scope atomics (2
// contributors per q-row, last arriver finalizes — r6-validated tail).
// ---------------------------------------------------------------------------
__global__ __launch_bounds__(256, 2) void k_attn(
    const unsigned short* __restrict__ Qh, const unsigned short* __restrict__ Ql,
    const unsigned short* __restrict__ Kh, const unsigned short* __restrict__ Kl,
    const float4* __restrict__ Vpp, float* __restrict__ partsum,
    unsigned int* __restrict__ cnt, const float* __restrict__ co_b,
    float* __restrict__ out) {
  __shared__ __align__(16) short Kt[2][2][32 * 264];  // [buf][hi/lo][32 rows pad 264]
  __shared__ __align__(16) float4 Vt[2][32];
  const int t = threadIdx.x;
  const int lane = t & 63, wv = t >> 6;
  const int l31 = lane & 31, half = lane >> 5;
  const int b = blockIdx.x & 7;       // batch ~pinned per-XCD for K L2 locality
  const int qt = (blockIdx.x >> 3) & 31;
  const int jh = blockIdx.x >> 8;     // j-half 0/1
  const int qrow = qt * 128 + wv * 32 + l31;
  const size_t qoff = ((size_t)b * 4096 + qrow) * 256 + half * 8;
  bf16x8 qfh[16], qfl[16];            // Q hi/lo resident (B-operand layout)
#pragma unroll
  for (int kc = 0; kc < 16; ++kc) {
    qfh[kc] = *(const bf16x8*)(Qh + qoff + kc * 16);
    qfl[kc] = *(const bf16x8*)(Ql + qoff + kc * 16);
  }
  const unsigned short* Kgh = Kh + (size_t)b * 4096 * 256;
  const unsigned short* Kgl = Kl + (size_t)b * 4096 * 256;
  const float4* Vg = Vpp + (size_t)b * 4096;
  const int r0 = t >> 5;              // staging row within 8-row group
  const int sseg = (t & 31) * 8;      // staging column segment
  float a0 = 0.f, a1 = 0.f, a2 = 0.f, al = 0.f;
  const int jt0 = jh * 64;
  {  // prologue: stage tile jt0 into buf 0
    const int jbase = jt0 * 32;
#pragma unroll
    for (int i = 0; i < 4; ++i) {
      const int row = i * 8 + r0;
      const size_t g = (size_t)(jbase + row) * 256 + sseg;
      *(bf16x8*)&Kt[0][0][row * 264 + sseg] = *(const bf16x8*)(Kgh + g);
      *(bf16x8*)&Kt[0][1][row * 264 + sseg] = *(const bf16x8*)(Kgl + g);
    }
    if (t < 32) Vt[0][t] = Vg[jbase + t];
  }
  __syncthreads();
  for (int it = 0; it < 64; ++it) {
    const int cur = it & 1, nxt = cur ^ 1;
    const bool pf = (it < 63);
    bf16x8 th[4], tl[4];
    float4 vpf = make_float4(0.f, 0.f, 0.f, 0.f);
    if (pf) {  // issue next-tile loads early; latency hides under compute
      const int jb2 = (jt0 + it + 1) * 32;
#pragma unroll
      for (int i = 0; i < 4; ++i) {
        const size_t g = (size_t)(jb2 + i * 8 + r0) * 256 + sseg;
        th[i] = *(const bf16x8*)(Kgh + g);
        tl[i] = *(const bf16x8*)(Kgl + g);
      }
      if (t < 32) vpf = Vg[jb2 + t];
    }
    // S^T[32j][32q] = K·Q^T; three accumulators = three 16-long MFMA chains
    f32x16 sA, sB, sC;
#pragma unroll
    for (int r = 0; r < 16; ++r) { sA[r] = 0.f; sB[r] = 0.f; sC[r] = 0.f; }
    const short* KH = Kt[cur][0];
    const short* KL = Kt[cur][1];
#pragma unroll
    for (int kc = 0; kc < 16; ++kc) {
      bf16x8 kh = *(const bf16x8*)&KH[l31 * 264 + kc * 16 + half * 8];
      bf16x8 kl = *(const bf16x8*)&KL[l31 * 264 + kc * 16 + half * 8];
      sA = mfma32(kh, qfh[kc], sA);   // Kh·Qh
      sB = mfma32(kh, qfl[kc], sB);   // Kh·Ql
      sC = mfma32(kl, qfh[kc], sC);   // Kl·Qh
    }
#pragma unroll
    for (int r = 0; r < 16; ++r) {
      const float p = __builtin_amdgcn_exp2f(sA[r] + sB[r] + sC[r]);
      const float4 vj = Vt[cur][(r & 3) + 8 * (r >> 2) + 4 * half];
      a0 += p * vj.x; a1 += p * vj.y; a2 += p * vj.z; al += p;
    }
    if (pf) {  // write prefetched tile into the buffer consumed 2 tiles ago
#pragma unroll
      for (int i = 0; i < 4; ++i) {
        const int row = i * 8 + r0;
        *(bf16x8*)&Kt[nxt][0][row * 264 + sseg] = th[i];
        *(bf16x8*)&Kt[nxt][1][row * 264 + sseg] = tl[i];
      }
      if (t < 32) Vt[nxt][t] = vpf;
    }
    __syncthreads();  // single barrier per tile
  }
  // halves hold disjoint j-sets for the same q: one swap-add finishes the sum
  a0 += __shfl_xor(a0, 32);
  a1 += __shfl_xor(a1, 32);
  a2 += __shfl_xor(a2, 32);
  al += __shfl_xor(al, 32);
  if (half == 0) {
    const int idx = b * 4096 + qrow;
    float* ps = partsum + (size_t)idx * 4;
    atomicAdd(ps + 0, a0);
    atomicAdd(ps + 1, a1);
    atomicAdd(ps + 2, a2);
    atomicAdd(ps + 3, al);
    __threadfence();
    const unsigned int old = atomicAdd(&cnt[idx], 1u);
    if (old == 1u) {   // last arriver finalizes; atomic reads are coherent
      const float s0 = atomicAdd(ps + 0, 0.f);
      const float s1 = atomicAdd(ps + 1, 0.f);
      const float s2 = atomicAdd(ps + 2, 0.f);
      const float sl = atomicAdd(ps + 3, 0.f);
      const float rl = 1.f / sl;
      out[(size_t)idx * 3 + 0] = s0 * rl + co_b[0];
      out[(size_t)idx * 3 + 1] = s1 * rl + co_b[1];
      out[(size_t)idx * 3 + 2] = s2 * rl + co_b[2];
    }
  }
}

// ---------------------------------------------------------------------------
extern "C" void kernel_launch(void* const* d_in, const int* in_sizes, int n_in,
                              void* d_out, int out_size, void* d_ws, size_t ws_size,
                              hipStream_t stream) {
  const float* x = (const float*)d_in[0];
  const float* fc1_w = (const float*)d_in[1];
  const float* fc1_b = (const float*)d_in[2];
  const float* c1q_w = (const float*)d_in[3];
  const float* c1q_b = (const float*)d_in[4];
  const float* c2q_w = (const float*)d_in[5];
  const float* c2q_b = (const float*)d_in[6];
  const float* c3q_w = (const float*)d_in[7];
  const float* c3q_b = (const float*)d_in[8];
  const float* c3k_w = (const float*)d_in[9];
  const float* c3k_b = (const float*)d_in[10];
  const float* c1v_w = (const float*)d_in[11];
  const float* c1v_b = (const float*)d_in[12];
  const float* c2v_w = (const float*)d_in[13];
  const float* c2v_b = (const float*)d_in[14];
  const float* c3v_w = (const float*)d_in[15];
  const float* c3v_b = (const float*)d_in[16];
  const float* bn1q_g = (const float*)d_in[17];
  const float* bn1q_be = (const float*)d_in[18];
  const float* bn1q_m = (const float*)d_in[19];
  const float* bn1q_v = (const float*)d_in[20];
  const float* bn2q_g = (const float*)d_in[21];
  const float* bn2q_be = (const float*)d_in[22];
  const float* bn2q_m = (const float*)d_in[23];
  const float* bn2q_v = (const float*)d_in[24];
  const float* bn1k_g = (const float*)d_in[25];
  const float* bn1k_be = (const float*)d_in[26];
  const float* bn1k_m = (const float*)d_in[27];
  const float* bn1k_v = (const float*)d_in[28];
  const float* bn2k_g = (const float*)d_in[29];
  const float* bn2k_be = (const float*)d_in[30];
  const float* bn2k_m = (const float*)d_in[31];
  const float* bn2k_v = (const float*)d_in[32];
  const float* bn1v_g = (const float*)d_in[33];
  const float* bn1v_be = (const float*)d_in[34];
  const float* bn1v_m = (const float*)d_in[35];
  const float* bn1v_v = (const float*)d_in[36];
  const float* bn2v_g = (const float*)d_in[37];
  const float* bn2v_be = (const float*)d_in[38];
  const float* bn2v_m = (const float*)d_in[39];
  const float* bn2v_v = (const float*)d_in[40];
  const float* co_w = (const float*)d_in[41];
  const float* co_b = (const float*)d_in[42];

  char* ws = (char*)d_ws;
  float* h_t = (float*)(ws + 0);                            // 1 MB [8][128][256]
  float* T1q = (float*)(ws + 1048576);                      // 512KB each
  float* T1k = (float*)(ws + 1572864);
  float* T1v = (float*)(ws + 2097152);
  unsigned short* Q2H = (unsigned short*)(ws + 2621440);    // 512KB each, [8][256][128]
  unsigned short* Q2L = (unsigned short*)(ws + 3145728);
  unsigned short* K2H = (unsigned short*)(ws + 3670016);
  unsigned short* K2L = (unsigned short*)(ws + 4194304);
  float* V2F = (float*)(ws + 4718592);                      // 1MB fp32 [8][128][256]
  unsigned short* QhB = (unsigned short*)(ws + 5767168);    // 16MB each, [8][4096][256]
  unsigned short* QlB = (unsigned short*)(ws + 22544384);
  unsigned short* KhB = (unsigned short*)(ws + 39321600);
  unsigned short* KlB = (unsigned short*)(ws + 56098816);
  float4* Vpp = (float4*)(ws + 72876032);                   // 512KB [8][4096] f4
  float* partsum = (float*)(ws + 73416704);                 // 512KB [8][4096][4] f32
  unsigned int* cnt = (unsigned int*)(ws + 73940992);       // 128KB [8][4096] u32
  // total ws usage: ~71 MB

  // zero the atomic-combine buffers (captured into the graph; runs per replay)
  hipMemsetAsync(ws + 73416704, 0, 524288 + 131072, stream);

  k_fc1<<<8192, 256, 0, stream>>>(x, fc1_w, fc1_b, h_t);
  k_conv1<<<dim3(512, 2), 256, 0, stream>>>(
      h_t, c1q_w, c1q_b, c1v_w, c1v_b,
      bn1q_g, bn1q_be, bn1q_m, bn1q_v,
      bn1k_g, bn1k_be, bn1k_m, bn1k_v,
      bn1v_g, bn1v_be, bn1v_m, bn1v_v,
      T1q, T1k, T1v);
  k_conv2<<<dim3(8, 3, 8), 256, 0, stream>>>(
      T1q, T1k, T1v, c2q_w, c2q_b, c2v_w, c2v_b,
      bn2q_g, bn2q_be, bn2q_m, bn2q_v,
      bn2k_g, bn2k_be, bn2k_m, bn2k_v,
      bn2v_g, bn2v_be, bn2v_m, bn2v_v,
      Q2H, Q2L, K2H, K2L, V2F);
  k_conv3all<<<dim3(64, 8, 3), 256, 0, stream>>>(
      c3q_w, c3q_b, c3k_w, c3k_b, Q2H, Q2L, K2H, K2L,
      QhB, QlB, KhB, KlB, c3v_w, c3v_b, V2F, co_w, Vpp);
  k_attn<<<512, 256, 0, stream>>>(QhB, QlB, KhB, KlB, Vpp, partsum, cnt,
                                  co_b, (float*)d_out);
}